// Round 1
// baseline (2862.055 us; speedup 1.0000x reference)
//
#include <hip/hip_runtime.h>

#define D_MODEL 528
#define NH 16
#define FEAT 16
#define HD 33          // head_dim = 2*FEAT+1
#define WIN 64
#define EPSF 1e-9f

// ---------------- generic fp32 tiled GEMM: C[M,N] = A[M,K] @ W[K,N] (+= if BETA) ----
template<int BETA>
__global__ __launch_bounds__(256) void gemm_f32(const float* __restrict__ A,
                                                const float* __restrict__ W,
                                                float* __restrict__ C,
                                                int M, int N, int K) {
  __shared__ float As[16][65];   // As[k][m]
  __shared__ float Ws[16][64];   // Ws[k][n]
  const int bm = blockIdx.x * 64, bn = blockIdx.y * 64;
  const int tid = threadIdx.x;
  const int tm = (tid / 16) * 4;
  const int tn = (tid % 16) * 4;
  float acc[4][4] = {};
  for (int k0 = 0; k0 < K; k0 += 16) {
    for (int i = tid; i < 64 * 16; i += 256) {
      int m = i / 16, k = i % 16;
      float a = 0.f;
      if (bm + m < M) a = A[(size_t)(bm + m) * K + k0 + k];
      As[k][m] = a;
    }
    for (int i = tid; i < 16 * 64; i += 256) {
      int k = i / 64, n = i % 64;
      float w = 0.f;
      if (bn + n < N) w = W[(size_t)(k0 + k) * N + bn + n];
      Ws[k][n] = w;
    }
    __syncthreads();
#pragma unroll
    for (int k = 0; k < 16; ++k) {
      float av[4], wv[4];
#pragma unroll
      for (int i = 0; i < 4; ++i) av[i] = As[k][tm + i];
#pragma unroll
      for (int j = 0; j < 4; ++j) wv[j] = Ws[k][tn + j];
#pragma unroll
      for (int i = 0; i < 4; ++i)
#pragma unroll
        for (int j = 0; j < 4; ++j) acc[i][j] += av[i] * wv[j];
    }
    __syncthreads();
  }
#pragma unroll
  for (int i = 0; i < 4; ++i)
#pragma unroll
    for (int j = 0; j < 4; ++j) {
      int m = bm + tm + i, n = bn + tn + j;
      if (m < M && n < N) {
        size_t idx = (size_t)m * N + n;
        if (BETA) C[idx] += acc[i][j];
        else C[idx] = acc[i][j];
      }
    }
}

// ---------------- linear attention: kv[bh][d][e] and ksum[bh][d] ----------------
__global__ __launch_bounds__(256) void lin_kv(const float* __restrict__ k_lin,
                                              const float* __restrict__ v_lin,
                                              float* __restrict__ kv,
                                              float* __restrict__ ksum,
                                              int B, int S) {
  const int bh = blockIdx.x;          // 0..B*NH-1
  const int b = bh / NH, h = bh % NH;
  const int tid = threadIdx.x;
  __shared__ float kraw[64][17];
  __shared__ float vsh[64][34];
  float acc[5] = {0.f, 0.f, 0.f, 0.f, 0.f};
  for (int n0 = 0; n0 < S; n0 += 64) {
    for (int i = tid; i < 64 * FEAT; i += 256) {
      int n = i / FEAT, f = i % FEAT;
      kraw[n][f] = k_lin[(size_t)(b * S + n0 + n) * (NH * FEAT) + h * FEAT + f];
    }
    for (int i = tid; i < 64 * HD; i += 256) {
      int n = i / HD, e = i % HD;
      vsh[n][e] = v_lin[(size_t)(b * S + n0 + n) * D_MODEL + h * HD + e];
    }
    __syncthreads();
#pragma unroll
    for (int r = 0; r < 5; ++r) {
      int idx = tid + 256 * r;
      if (idx < HD * 34) {
        int d = idx / 34, c = idx % 34;   // c<33: kv column; c==33: ksum
        float a = acc[r];
        for (int n = 0; n < 64; ++n) {
          float ke;
          if (d == 0) ke = 1.f;
          else if (d < 17) ke = kraw[n][d - 1];
          else { float kk = kraw[n][d - 17]; ke = 0.5f * kk * kk; }
          float x = (c < HD) ? vsh[n][c] : 1.f;
          a += ke * x;
        }
        acc[r] = a;
      }
    }
    __syncthreads();
  }
#pragma unroll
  for (int r = 0; r < 5; ++r) {
    int idx = tid + 256 * r;
    if (idx < HD * 34) {
      int d = idx / 34, c = idx % 34;
      if (c < HD) kv[((size_t)bh * HD + d) * HD + c] = acc[r];
      else ksum[(size_t)bh * HD + d] = acc[r];
    }
  }
}

// ---------------- linear attention output: lin_pre[b,n,h*33+e] -------------------
__global__ __launch_bounds__(256) void lin_out_k(const float* __restrict__ q_lin,
                                                 const float* __restrict__ kv,
                                                 const float* __restrict__ ksum,
                                                 const int* __restrict__ mask,
                                                 float* __restrict__ lin_pre,
                                                 int B, int S) {
  const int bs = blockIdx.x;           // b*S + n
  const int b = bs / S;
  __shared__ float qsh[NH][17];
  for (int i = threadIdx.x; i < NH * FEAT; i += 256)
    qsh[i / FEAT][i % FEAT] = q_lin[(size_t)bs * (NH * FEAT) + i];
  __syncthreads();
  const int msk = mask[bs];
  (void)b;
  for (int o = threadIdx.x; o < D_MODEL; o += 256) {
    int h = o / HD, e = o % HD;
    const float* kvh = kv + ((size_t)(b * NH + h) * HD) * HD;
    float qsum = 1.f;
    float qkv = kvh[e];               // d = 0 row (qe=1)
#pragma unroll
    for (int f = 0; f < FEAT; ++f) {
      float q = qsh[h][f];
      float q2 = 0.5f * q * q;
      qsum += q + q2;
      qkv += q * kvh[(1 + f) * HD + e] + q2 * kvh[(17 + f) * HD + e];
    }
    float z = qsum * ksum[(size_t)(b * NH + h) * HD + e];
    float outv = qkv / (z + EPSF);
    if (msk == 0) outv = 0.f;
    lin_pre[(size_t)bs * D_MODEL + o] = outv;
  }
}

// ---------------- banded ("window") attention, flash-style -----------------------
__global__ __launch_bounds__(256) void win_attn(const float* __restrict__ qw,
                                                const float* __restrict__ kw,
                                                const float* __restrict__ vw,
                                                const int* __restrict__ mask,
                                                float* __restrict__ win_pre,
                                                int B, int S) {
  const int n0 = blockIdx.x * 64;
  const int bh = blockIdx.y;
  const int b = bh >> 4, h = bh & 15;
  const int tid = threadIdx.x;
  __shared__ float qs[64][35], ks[64][35], vs[64][35];
  __shared__ float ps[64][65];
  __shared__ float accs[64][35];
  __shared__ float mrow[64], lrow[64], frow[64];
  const float scale = 0.17407765595569785f;   // 1/sqrt(33)

  for (int i = tid; i < 64 * HD; i += 256) {
    int qi = i / HD, e = i % HD;
    qs[qi][e] = qw[(size_t)(b * S + n0 + qi) * D_MODEL + h * HD + e];
    accs[qi][e] = 0.f;
  }
  if (tid < 64) { mrow[tid] = -1e30f; lrow[tid] = 0.f; }
  __syncthreads();

  const int mmax = min(S, n0 + 64 + WIN - 1);   // keys m < mmax
  for (int m0 = 0; m0 < mmax; m0 += 64) {
    for (int i = tid; i < 64 * HD; i += 256) {
      int kj = i / HD, e = i % HD;
      int m = m0 + kj;
      float kval = 0.f, vval = 0.f;
      if (m < S) {
        size_t base = (size_t)(b * S + m) * D_MODEL + h * HD + e;
        kval = kw[base];
        vval = vw[base];
      }
      ks[kj][e] = kval;
      vs[kj][e] = vval;
    }
    __syncthreads();
    // scores
    for (int i = tid; i < 64 * 64; i += 256) {
      int qi = i >> 6, kj = i & 63;
      int m = m0 + kj, n = n0 + qi;
      float s = -1e30f;
      if (m < S && m <= n + WIN - 1 && mask[b * S + m] != 0) {
        float dot = 0.f;
#pragma unroll
        for (int e = 0; e < HD; ++e) dot += qs[qi][e] * ks[kj][e];
        s = dot * scale;
      }
      ps[qi][kj] = s;
    }
    __syncthreads();
    // online softmax per query row
    if (tid < 64) {
      int qi = tid;
      float mo = mrow[qi], mt = -1e30f;
#pragma unroll 8
      for (int j = 0; j < 64; ++j) mt = fmaxf(mt, ps[qi][j]);
      float mn = fmaxf(mo, mt);
      if (mn <= -1e29f) {
        frow[qi] = 1.f;
        for (int j = 0; j < 64; ++j) ps[qi][j] = 0.f;
      } else {
        float f = __expf(mo - mn);
        float sum = 0.f;
        for (int j = 0; j < 64; ++j) {
          float p = __expf(ps[qi][j] - mn);
          ps[qi][j] = p;
          sum += p;
        }
        frow[qi] = f;
        lrow[qi] = lrow[qi] * f + sum;
        mrow[qi] = mn;
      }
    }
    __syncthreads();
    // PV accumulate
    for (int i = tid; i < 64 * HD; i += 256) {
      int qi = i / HD, e = i % HD;
      float a = accs[qi][e] * frow[qi];
#pragma unroll 8
      for (int j = 0; j < 64; ++j) a += ps[qi][j] * vs[j][e];
      accs[qi][e] = a;
    }
    __syncthreads();
  }
  for (int i = tid; i < 64 * HD; i += 256) {
    int qi = i / HD, e = i % HD;
    float l = lrow[qi];
    float o = (l > 0.f) ? accs[qi][e] / l : 0.f;
    win_pre[(size_t)(b * S + n0 + qi) * D_MODEL + h * HD + e] = o;
  }
}

extern "C" void kernel_launch(void* const* d_in, const int* in_sizes, int n_in,
                              void* d_out, int out_size, void* d_ws, size_t ws_size,
                              hipStream_t stream) {
  const float* x      = (const float*)d_in[0];
  const int*   mask   = (const int*)d_in[1];
  const float* Wq_lin = (const float*)d_in[2];
  const float* Wk_lin = (const float*)d_in[3];
  const float* Wv_lin = (const float*)d_in[4];
  const float* Wo_lin = (const float*)d_in[5];
  const float* Wq_win = (const float*)d_in[6];
  const float* Wk_win = (const float*)d_in[7];
  const float* Wv_win = (const float*)d_in[8];
  const float* Wo_win = (const float*)d_in[9];
  float* out = (float*)d_out;

  const int BS = in_sizes[1];     // B*S
  const int B = 2;
  const int S = BS / B;

  float* ws = (float*)d_ws;
  float* q_lin   = ws; ws += (size_t)BS * NH * FEAT;   // 4096*256
  float* k_lin   = ws; ws += (size_t)BS * NH * FEAT;
  float* v_lin   = ws; ws += (size_t)BS * D_MODEL;
  float* q_win   = ws; ws += (size_t)BS * D_MODEL;
  float* k_win   = ws; ws += (size_t)BS * D_MODEL;
  float* v_win   = ws; ws += (size_t)BS * D_MODEL;
  float* lin_pre = ws; ws += (size_t)BS * D_MODEL;
  float* win_pre = ws; ws += (size_t)BS * D_MODEL;
  float* kv      = ws; ws += (size_t)B * NH * HD * HD;
  float* ksum    = ws; ws += (size_t)B * NH * HD;

  const int M = BS, K = D_MODEL;
  dim3 blk(256);
  dim3 gq((M + 63) / 64, (NH * FEAT + 63) / 64);
  dim3 gd((M + 63) / 64, (D_MODEL + 63) / 64);

  // projections
  gemm_f32<0><<<gq, blk, 0, stream>>>(x, Wq_lin, q_lin, M, NH * FEAT, K);
  gemm_f32<0><<<gq, blk, 0, stream>>>(x, Wk_lin, k_lin, M, NH * FEAT, K);
  gemm_f32<0><<<gd, blk, 0, stream>>>(x, Wv_lin, v_lin, M, D_MODEL, K);
  gemm_f32<0><<<gd, blk, 0, stream>>>(x, Wq_win, q_win, M, D_MODEL, K);
  gemm_f32<0><<<gd, blk, 0, stream>>>(x, Wk_win, k_win, M, D_MODEL, K);
  gemm_f32<0><<<gd, blk, 0, stream>>>(x, Wv_win, v_win, M, D_MODEL, K);

  // linear attention
  lin_kv<<<dim3(B * NH), blk, 0, stream>>>(k_lin, v_lin, kv, ksum, B, S);
  lin_out_k<<<dim3(BS), blk, 0, stream>>>(q_lin, kv, ksum, mask, lin_pre, B, S);

  // banded attention
  win_attn<<<dim3(S / 64, B * NH), blk, 0, stream>>>(q_win, k_win, v_win, mask,
                                                     win_pre, B, S);

  // output projections: out = lin_pre @ Wo_lin + win_pre @ Wo_win
  gemm_f32<0><<<gd, blk, 0, stream>>>(lin_pre, Wo_lin, out, M, D_MODEL, K);
  gemm_f32<1><<<gd, blk, 0, stream>>>(win_pre, Wo_win, out, M, D_MODEL, K);
}

// Round 2
// 544.083 us; speedup vs baseline: 5.2603x; 5.2603x over previous
//
#include <hip/hip_runtime.h>

#define D_MODEL 528
#define NH 16
#define FEAT 16
#define HD 33
#define WIN 64
#define EPSF 1e-9f
#define SCALE_W 0.17407765595569785f   // 1/sqrt(33)

typedef float f32x4 __attribute__((ext_vector_type(4)));
typedef short short8 __attribute__((ext_vector_type(8)));

__device__ inline ushort f2bf(float f) {
  uint u = __float_as_uint(f);
  uint r = u + 0x7fffu + ((u >> 16) & 1u);
  return (ushort)(r >> 16);
}

// ---------------- fp32 → bf16 elementwise ----------------
__global__ __launch_bounds__(256) void cvt_f32_bf16(const float* __restrict__ in,
                                                    ushort* __restrict__ out, int n) {
  int stride = gridDim.x * 256;
  for (int i = blockIdx.x * 256 + threadIdx.x; i < n; i += stride) out[i] = f2bf(in[i]);
}

// ---------------- W[K][N] fp32 -> Wt[N][K] bf16 (transpose+convert) --------------
__global__ __launch_bounds__(256) void wt_cvt(const float* __restrict__ W,
                                              ushort* __restrict__ Wt, int K, int N) {
  __shared__ float t[32][33];
  int bx = blockIdx.x * 32, by = blockIdx.y * 32;   // bx: N, by: K
  int tx = threadIdx.x & 31, ty = threadIdx.x >> 5;
  for (int yy = ty; yy < 32; yy += 8) {
    float v = 0.f;
    int kk = by + yy, nn = bx + tx;
    if (kk < K && nn < N) v = W[(size_t)kk * N + nn];
    t[yy][tx] = v;
  }
  __syncthreads();
  for (int yy = ty; yy < 32; yy += 8) {
    int nn = bx + yy, kk = by + tx;
    if (nn < N && kk < K) Wt[(size_t)nn * K + kk] = f2bf(t[tx][yy]);
  }
}

// ---------------- fp32 tiled GEMM: C[M,N] = A[M,K] @ W[K,N] (+= if BETA) ---------
// BM=BN=64, BK=48 (528 = 11*48). M must be a multiple of 64, K a multiple of 48.
template<int BETA>
__global__ __launch_bounds__(256) void gemm_f32(const float* __restrict__ A,
                                                const float* __restrict__ W,
                                                float* __restrict__ C,
                                                int M, int N, int K) {
  __shared__ float As[48][68];   // [k][m]
  __shared__ float Ws[48][68];   // [k][n]
  const int bm = blockIdx.x * 64, bn = blockIdx.y * 64;
  const int tid = threadIdx.x;
  const int tm = (tid >> 4) * 4, tn = (tid & 15) * 4;
  float acc[4][4] = {};
  for (int k0 = 0; k0 < K; k0 += 48) {
    float4 a_ld[3], w_ld[3];
#pragma unroll
    for (int p = 0; p < 3; ++p) {
      int fl = tid + p * 256;
      int m = fl / 12, c4 = (fl % 12) * 4;
      a_ld[p] = *(const float4*)&A[(size_t)(bm + m) * K + k0 + c4];
      int kr = fl >> 4, n4 = (fl & 15) * 4;
      if (bn + n4 < N) w_ld[p] = *(const float4*)&W[(size_t)(k0 + kr) * N + bn + n4];
      else w_ld[p] = make_float4(0.f, 0.f, 0.f, 0.f);
    }
    __syncthreads();
#pragma unroll
    for (int p = 0; p < 3; ++p) {
      int fl = tid + p * 256;
      int m = fl / 12, k = (fl % 12) * 4;
      As[k + 0][m] = a_ld[p].x; As[k + 1][m] = a_ld[p].y;
      As[k + 2][m] = a_ld[p].z; As[k + 3][m] = a_ld[p].w;
      int kr = fl >> 4, n4 = (fl & 15) * 4;
      *(float4*)&Ws[kr][n4] = w_ld[p];
    }
    __syncthreads();
#pragma unroll 6
    for (int k = 0; k < 48; ++k) {
      float4 av = *(const float4*)&As[k][tm];
      float4 wv = *(const float4*)&Ws[k][tn];
      float a0 = av.x, a1 = av.y, a2 = av.z, a3 = av.w;
      float w0 = wv.x, w1 = wv.y, w2 = wv.z, w3 = wv.w;
      acc[0][0] += a0 * w0; acc[0][1] += a0 * w1; acc[0][2] += a0 * w2; acc[0][3] += a0 * w3;
      acc[1][0] += a1 * w0; acc[1][1] += a1 * w1; acc[1][2] += a1 * w2; acc[1][3] += a1 * w3;
      acc[2][0] += a2 * w0; acc[2][1] += a2 * w1; acc[2][2] += a2 * w2; acc[2][3] += a2 * w3;
      acc[3][0] += a3 * w0; acc[3][1] += a3 * w1; acc[3][2] += a3 * w2; acc[3][3] += a3 * w3;
    }
  }
#pragma unroll
  for (int i = 0; i < 4; ++i)
#pragma unroll
    for (int j = 0; j < 4; ++j) {
      int m = bm + tm + i, n = bn + tn + j;
      if (n < N) {
        size_t idx = (size_t)m * N + n;
        if (BETA) C[idx] += acc[i][j];
        else C[idx] = acc[i][j];
      }
    }
}

// ---------------- bf16 MFMA GEMM: C[M,N] = A[M,K] @ Bt[N,K]^T --------------------
// MODE 0: store bf16; MODE 1: fp32 +=. BM=BN=64, BK=32, 4 waves.
template<int MODE>
__global__ __launch_bounds__(256) void gemm_bf16(const ushort* __restrict__ A,
                                                 const ushort* __restrict__ Bt,
                                                 void* __restrict__ Cp,
                                                 int M, int N, int K) {
  __shared__ ushort As[64][40];
  __shared__ ushort Bs[64][40];
  const int bm = blockIdx.x * 64, bn = blockIdx.y * 64;
  const int tid = threadIdx.x;
  const int lane = tid & 63, w = tid >> 6;
  const int lo = lane & 15, hi = lane >> 4;
  const int row_s = tid >> 2, ch = tid & 3;
  f32x4 acc[4];
#pragma unroll
  for (int mb = 0; mb < 4; ++mb) acc[mb] = (f32x4){0.f, 0.f, 0.f, 0.f};
  const short8 zv = {0, 0, 0, 0, 0, 0, 0, 0};

  for (int k0 = 0; k0 < K; k0 += 32) {
    short8 av = zv, bv = zv;
    if (k0 + ch * 8 < K) {
      av = *(const short8*)&A[(size_t)(bm + row_s) * K + k0 + ch * 8];
      if (bn + row_s < N) bv = *(const short8*)&Bt[(size_t)(bn + row_s) * K + k0 + ch * 8];
    }
    __syncthreads();
    *(short8*)&As[row_s][ch * 8] = av;
    *(short8*)&Bs[row_s][ch * 8] = bv;
    __syncthreads();
    short8 bf = *(const short8*)&Bs[16 * w + lo][8 * hi];
#pragma unroll
    for (int mb = 0; mb < 4; ++mb) {
      short8 af = *(const short8*)&As[16 * mb + lo][8 * hi];
      acc[mb] = __builtin_amdgcn_mfma_f32_16x16x32_bf16(af, bf, acc[mb], 0, 0, 0);
    }
  }
#pragma unroll
  for (int mb = 0; mb < 4; ++mb)
#pragma unroll
    for (int r = 0; r < 4; ++r) {
      int row = bm + 16 * mb + hi * 4 + r;
      int col = bn + 16 * w + lo;
      if (col < N) {
        if (MODE == 0) ((ushort*)Cp)[(size_t)row * N + col] = f2bf(acc[mb][r]);
        else ((float*)Cp)[(size_t)row * N + col] += acc[mb][r];
      }
    }
}

// ---------------- linear attention: partial kv over S-chunks ---------------------
__global__ __launch_bounds__(256) void lin_kv_part(const float* __restrict__ k_lin,
                                                   const float* __restrict__ v_lin,
                                                   float* __restrict__ kvp,
                                                   int B, int S) {
  const int bh = blockIdx.x;
  const int chunk = blockIdx.y;            // 8 chunks of 256 rows
  const int b = bh / NH, h = bh % NH;
  const int tid = threadIdx.x;
  __shared__ float kraw[64][17];
  __shared__ float vsh[64][34];
  float acc[5] = {0.f, 0.f, 0.f, 0.f, 0.f};
  const int nbeg = chunk * 256, nend = nbeg + 256;
  for (int n0 = nbeg; n0 < nend; n0 += 64) {
    for (int i = tid; i < 64 * FEAT; i += 256) {
      int n = i / FEAT, f = i % FEAT;
      kraw[n][f] = k_lin[(size_t)(b * S + n0 + n) * (NH * FEAT) + h * FEAT + f];
    }
    for (int i = tid; i < 64 * HD; i += 256) {
      int n = i / HD, e = i % HD;
      vsh[n][e] = v_lin[(size_t)(b * S + n0 + n) * D_MODEL + h * HD + e];
    }
    __syncthreads();
#pragma unroll
    for (int r = 0; r < 5; ++r) {
      int idx = tid + 256 * r;
      if (idx < HD * 34) {
        int d = idx / 34, c = idx % 34;
        float a = acc[r];
        for (int n = 0; n < 64; ++n) {
          float ke;
          if (d == 0) ke = 1.f;
          else if (d < 17) ke = kraw[n][d - 1];
          else { float kk = kraw[n][d - 17]; ke = 0.5f * kk * kk; }
          float x = (c < HD) ? vsh[n][c] : 1.f;
          a += ke * x;
        }
        acc[r] = a;
      }
    }
    __syncthreads();
  }
  float* dst = kvp + (size_t)(bh * 8 + chunk) * 1122;
#pragma unroll
  for (int r = 0; r < 5; ++r) {
    int idx = tid + 256 * r;
    if (idx < 1122) dst[idx] = acc[r];
  }
}

__global__ __launch_bounds__(256) void lin_red(const float* __restrict__ kvp,
                                               float* __restrict__ kvr) {
  int bh = blockIdx.x;
  for (int i = threadIdx.x; i < 1122; i += 256) {
    float s = 0.f;
#pragma unroll
    for (int c = 0; c < 8; ++c) s += kvp[(size_t)(bh * 8 + c) * 1122 + i];
    kvr[(size_t)bh * 1122 + i] = s;
  }
}

// ---------------- linear attention output ---------------------------------------
__global__ __launch_bounds__(256) void lin_out_k(const float* __restrict__ q_lin,
                                                 const float* __restrict__ kvr,
                                                 const int* __restrict__ mask,
                                                 float* __restrict__ lin_pre,
                                                 int B, int S) {
  const int bs = blockIdx.x;
  const int b = bs / S;
  __shared__ float qsh[NH][17];
  for (int i = threadIdx.x; i < NH * FEAT; i += 256)
    qsh[i / FEAT][i % FEAT] = q_lin[(size_t)bs * (NH * FEAT) + i];
  __syncthreads();
  const int msk = mask[bs];
  for (int o = threadIdx.x; o < D_MODEL; o += 256) {
    int h = o / HD, e = o % HD;
    const float* kvh = kvr + (size_t)(b * NH + h) * 1122;
    float qsum = 1.f;
    float qkv = kvh[e];
#pragma unroll
    for (int f = 0; f < FEAT; ++f) {
      float q = qsh[h][f];
      float q2 = 0.5f * q * q;
      qsum += q + q2;
      qkv += q * kvh[(1 + f) * 34 + e] + q2 * kvh[(17 + f) * 34 + e];
    }
    float z = qsum * kvh[e * 34 + 33];
    float outv = qkv / (z + EPSF);
    if (msk == 0) outv = 0.f;
    lin_pre[(size_t)bs * D_MODEL + o] = outv;
  }
}

// ---------------- banded attention, bf16 MFMA flash ------------------------------
__global__ __launch_bounds__(256) void win_attn_mfma(const ushort* __restrict__ qw,
                                                     const ushort* __restrict__ kw,
                                                     const ushort* __restrict__ vw,
                                                     const int* __restrict__ maskp,
                                                     ushort* __restrict__ win_pre,
                                                     int B, int S) {
  const int n0 = (gridDim.x - 1 - blockIdx.x) * 64;   // longest blocks first
  const int bh = blockIdx.y;
  const int b = bh >> 4, h = bh & 15;
  const int tid = threadIdx.x;
  const int lane = tid & 63, w = tid >> 6;
  const int lo = lane & 15, hi = lane >> 4;

  __shared__ ushort Ks[64][72];      // [kj][e], e zero-padded 33..63
  __shared__ ushort Vt[48][72];      // [e][kj], rows 33..47 zero
  __shared__ ushort Ps[4][16][72];   // per-wave P tile

  for (int i = tid; i < 64 * 72; i += 256) ((ushort*)Ks)[i] = 0;
  for (int i = tid; i < 48 * 72; i += 256) ((ushort*)Vt)[i] = 0;

  // Q fragments (A layout: row = lo, k = 32*st + 8*hi + j)
  short8 qf[2];
  const size_t qbase = ((size_t)(b * S + n0 + w * 16 + lo)) * D_MODEL + h * HD;
#pragma unroll
  for (int st = 0; st < 2; ++st)
#pragma unroll
    for (int j = 0; j < 8; ++j) {
      int e = 32 * st + 8 * hi + j;
      qf[st][j] = (e < HD) ? (short)qw[qbase + e] : (short)0;
    }

  f32x4 Oacc[3];
#pragma unroll
  for (int eb = 0; eb < 3; ++eb) Oacc[eb] = (f32x4){0.f, 0.f, 0.f, 0.f};
  float mreg[4] = {-1e30f, -1e30f, -1e30f, -1e30f};
  float lreg[4] = {0.f, 0.f, 0.f, 0.f};

  __syncthreads();

  const int mmax = min(S, n0 + 64 + WIN - 1);
  for (int m0 = 0; m0 < mmax; m0 += 64) {
    // stage K as [kj][e], V transposed as [e][kj]
    for (int i = tid; i < 64 * HD; i += 256) {
      int kj = i / HD;
      int e = i - kj * HD;
      int m = m0 + kj;
      ushort kvv = 0, vvv = 0;
      if (m < S) {
        size_t base = ((size_t)(b * S + m)) * D_MODEL + h * HD + e;
        kvv = kw[base];
        vvv = vw[base];
      }
      Ks[kj][e] = kvv;
      Vt[e][kj] = vvv;
    }
    __syncthreads();

    // QK^T
    f32x4 accS[4];
#pragma unroll
    for (int bb = 0; bb < 4; ++bb) accS[bb] = (f32x4){0.f, 0.f, 0.f, 0.f};
#pragma unroll
    for (int bb = 0; bb < 4; ++bb)
#pragma unroll
      for (int st = 0; st < 2; ++st) {
        short8 kf = *(const short8*)&Ks[16 * bb + lo][32 * st + 8 * hi];
        accS[bb] = __builtin_amdgcn_mfma_f32_16x16x32_bf16(qf[st], kf, accS[bb], 0, 0, 0);
      }

    // masks + online softmax (C-layout: row = hi*4+r, col = 16*bb+lo)
    int mcol[4], mk[4];
#pragma unroll
    for (int bb = 0; bb < 4; ++bb) {
      mcol[bb] = m0 + 16 * bb + lo;
      mk[bb] = (mcol[bb] < S) ? maskp[b * S + mcol[bb]] : 0;
    }
    float pv[4][4];
#pragma unroll
    for (int r = 0; r < 4; ++r) {
      int n = n0 + w * 16 + hi * 4 + r;
      float s[4];
#pragma unroll
      for (int bb = 0; bb < 4; ++bb) {
        bool valid = (mk[bb] != 0) && (mcol[bb] <= n + WIN - 1);
        s[bb] = valid ? accS[bb][r] * SCALE_W : -1e30f;
      }
      float mt = fmaxf(fmaxf(s[0], s[1]), fmaxf(s[2], s[3]));
      mt = fmaxf(mt, __shfl_xor(mt, 1));
      mt = fmaxf(mt, __shfl_xor(mt, 2));
      mt = fmaxf(mt, __shfl_xor(mt, 4));
      mt = fmaxf(mt, __shfl_xor(mt, 8));
      float mn = fmaxf(mreg[r], mt);
      float f = __expf(mreg[r] - mn);
      mreg[r] = mn;
      float ts = 0.f;
#pragma unroll
      for (int bb = 0; bb < 4; ++bb) { pv[bb][r] = __expf(s[bb] - mn); ts += pv[bb][r]; }
      ts += __shfl_xor(ts, 1);
      ts += __shfl_xor(ts, 2);
      ts += __shfl_xor(ts, 4);
      ts += __shfl_xor(ts, 8);
      lreg[r] = lreg[r] * f + ts;
#pragma unroll
      for (int eb = 0; eb < 3; ++eb) Oacc[eb][r] *= f;
    }

    // P -> LDS (bf16)
#pragma unroll
    for (int r = 0; r < 4; ++r)
#pragma unroll
      for (int bb = 0; bb < 4; ++bb)
        Ps[w][hi * 4 + r][16 * bb + lo] = f2bf(pv[bb][r]);
    __syncthreads();

    // PV
    short8 pf[2];
#pragma unroll
    for (int st = 0; st < 2; ++st)
      pf[st] = *(const short8*)&Ps[w][lo][32 * st + 8 * hi];
#pragma unroll
    for (int eb = 0; eb < 3; ++eb)
#pragma unroll
      for (int st = 0; st < 2; ++st) {
        short8 vf = *(const short8*)&Vt[16 * eb + lo][32 * st + 8 * hi];
        Oacc[eb] = __builtin_amdgcn_mfma_f32_16x16x32_bf16(pf[st], vf, Oacc[eb], 0, 0, 0);
      }
    __syncthreads();
  }

  float inv[4];
#pragma unroll
  for (int r = 0; r < 4; ++r) inv[r] = (lreg[r] > 0.f) ? 1.f / lreg[r] : 0.f;
#pragma unroll
  for (int eb = 0; eb < 3; ++eb) {
    int e = 16 * eb + lo;
    if (e < HD) {
#pragma unroll
      for (int r = 0; r < 4; ++r) {
        int n = n0 + w * 16 + hi * 4 + r;
        win_pre[((size_t)(b * S + n)) * D_MODEL + h * HD + e] = f2bf(Oacc[eb][r] * inv[r]);
      }
    }
  }
}

extern "C" void kernel_launch(void* const* d_in, const int* in_sizes, int n_in,
                              void* d_out, int out_size, void* d_ws, size_t ws_size,
                              hipStream_t stream) {
  const float* x      = (const float*)d_in[0];
  const int*   mask   = (const int*)d_in[1];
  const float* Wq_lin = (const float*)d_in[2];
  const float* Wk_lin = (const float*)d_in[3];
  const float* Wv_lin = (const float*)d_in[4];
  const float* Wo_lin = (const float*)d_in[5];
  const float* Wq_win = (const float*)d_in[6];
  const float* Wk_win = (const float*)d_in[7];
  const float* Wv_win = (const float*)d_in[8];
  const float* Wo_win = (const float*)d_in[9];
  float* out = (float*)d_out;

  const int BS = in_sizes[1];
  const int B = 2;
  const int S = BS / B;
  const int M = BS, K = D_MODEL;

  // fp32 workspace
  float* ws = (float*)d_ws;
  float* q_lin   = ws;  ws += (size_t)BS * NH * FEAT;
  float* k_lin   = ws;  ws += (size_t)BS * NH * FEAT;
  float* v_lin   = ws;  ws += (size_t)BS * D_MODEL;
  float* lin_pre = ws;  ws += (size_t)BS * D_MODEL;
  float* kvp     = ws;  ws += (size_t)B * NH * 8 * 1122;
  float* kvr     = ws;  ws += (size_t)B * NH * 1122;
  // bf16 workspace
  ushort* ub     = (ushort*)ws;
  ushort* x_bf   = ub;  ub += (size_t)BS * D_MODEL;
  ushort* qwb    = ub;  ub += (size_t)BS * D_MODEL;
  ushort* kwb    = ub;  ub += (size_t)BS * D_MODEL;
  ushort* vwb    = ub;  ub += (size_t)BS * D_MODEL;
  ushort* wpb    = ub;  ub += (size_t)BS * D_MODEL;
  ushort* WqT    = ub;  ub += (size_t)D_MODEL * D_MODEL;
  ushort* WkT    = ub;  ub += (size_t)D_MODEL * D_MODEL;
  ushort* WvT    = ub;  ub += (size_t)D_MODEL * D_MODEL;
  ushort* WoT    = ub;  ub += (size_t)D_MODEL * D_MODEL;

  dim3 blk(256);
  dim3 gq(M / 64, (NH * FEAT) / 64);          // 64 x 4
  dim3 gd(M / 64, (D_MODEL + 63) / 64);       // 64 x 9
  dim3 gt((D_MODEL + 31) / 32, (D_MODEL + 31) / 32);

  // bf16 conversions
  cvt_f32_bf16<<<2048, blk, 0, stream>>>(x, x_bf, BS * D_MODEL);
  wt_cvt<<<gt, blk, 0, stream>>>(Wq_win, WqT, D_MODEL, D_MODEL);
  wt_cvt<<<gt, blk, 0, stream>>>(Wk_win, WkT, D_MODEL, D_MODEL);
  wt_cvt<<<gt, blk, 0, stream>>>(Wv_win, WvT, D_MODEL, D_MODEL);
  wt_cvt<<<gt, blk, 0, stream>>>(Wo_win, WoT, D_MODEL, D_MODEL);

  // linear path (fp32)
  gemm_f32<0><<<gq, blk, 0, stream>>>(x, Wq_lin, q_lin, M, NH * FEAT, K);
  gemm_f32<0><<<gq, blk, 0, stream>>>(x, Wk_lin, k_lin, M, NH * FEAT, K);
  gemm_f32<0><<<gd, blk, 0, stream>>>(x, Wv_lin, v_lin, M, D_MODEL, K);
  lin_kv_part<<<dim3(B * NH, 8), blk, 0, stream>>>(k_lin, v_lin, kvp, B, S);
  lin_red<<<dim3(B * NH), blk, 0, stream>>>(kvp, kvr);
  lin_out_k<<<dim3(BS), blk, 0, stream>>>(q_lin, kvr, mask, lin_pre, B, S);
  gemm_f32<0><<<gd, blk, 0, stream>>>(lin_pre, Wo_lin, out, M, D_MODEL, K);

  // window path (bf16 MFMA)
  gemm_bf16<0><<<gd, blk, 0, stream>>>(x_bf, WqT, qwb, M, D_MODEL, K);
  gemm_bf16<0><<<gd, blk, 0, stream>>>(x_bf, WkT, kwb, M, D_MODEL, K);
  gemm_bf16<0><<<gd, blk, 0, stream>>>(x_bf, WvT, vwb, M, D_MODEL, K);
  win_attn_mfma<<<dim3(S / 64, B * NH), blk, 0, stream>>>(qwb, kwb, vwb, mask, wpb, B, S);
  gemm_bf16<1><<<gd, blk, 0, stream>>>(wpb, WoT, out, M, D_MODEL, K);
}

// Round 3
// 421.766 us; speedup vs baseline: 6.7859x; 1.2900x over previous
//
#include <hip/hip_runtime.h>

#define NH 16
#define FEAT 16
#define HD 33
#define DM 528
#define WIN 64
#define EPSF 1e-9f
#define K1C (0.17407765595569785f * 1.4426950408889634f)
#define K2C (4.0f * 1.4426950408889634f)

typedef float f32x4 __attribute__((ext_vector_type(4)));
typedef short short8 __attribute__((ext_vector_type(8)));

__device__ inline ushort f2bf(float f) {
  uint u = __float_as_uint(f);
  uint r = u + 0x7fffu + ((u >> 16) & 1u);
  return (ushort)(r >> 16);
}
__device__ inline float bf2f(ushort u) { return __uint_as_float(((uint)u) << 16); }

// ---------------- W[K][N] fp32 -> Wt[N][K] bf16 (transpose+convert) --------------
__global__ __launch_bounds__(256) void wt_cvt(const float* __restrict__ W,
                                              ushort* __restrict__ Wt, int K, int N) {
  __shared__ float t[32][33];
  int bx = blockIdx.x * 32, by = blockIdx.y * 32;
  int tx = threadIdx.x & 31, ty = threadIdx.x >> 5;
  for (int yy = ty; yy < 32; yy += 8) {
    float v = 0.f;
    int kk = by + yy, nn = bx + tx;
    if (kk < K && nn < N) v = W[(size_t)kk * N + nn];
    t[yy][tx] = v;
  }
  __syncthreads();
  for (int yy = ty; yy < 32; yy += 8) {
    int nn = bx + yy, kk = by + tx;
    if (nn < N && kk < K) Wt[(size_t)nn * K + kk] = f2bf(t[tx][yy]);
  }
}

// ---------------- pack Wq_lin | Wk_lin -> Wqk [528][512] fp32 --------------------
__global__ __launch_bounds__(256) void pack_qk(const float* __restrict__ Wq,
                                               const float* __restrict__ Wk,
                                               float* __restrict__ Wqk) {
  int i = blockIdx.x * 256 + threadIdx.x;
  if (i < DM * 512) {
    int k = i >> 9, n = i & 511;
    Wqk[i] = (n < 256) ? Wq[k * 256 + n] : Wk[k * 256 + n - 256];
  }
}

// ---------------- fp32 GEMM: C[M,N] = A[M,K] @ W[K,N]; 128x64, BK=48 -------------
__global__ __launch_bounds__(256) void gemm_f32(const float* __restrict__ A,
                                                const float* __restrict__ W,
                                                float* __restrict__ C,
                                                int M, int N, int K) {
  __shared__ float As[48][132];
  __shared__ float Ws[48][72];
  const int bm = blockIdx.x * 128, bn = blockIdx.y * 64;
  const int tid = threadIdx.x;
  const int tm2 = (tid >> 4) * 4, tn = (tid & 15) * 4;
  float acc[8][4] = {};
  for (int k0 = 0; k0 < K; k0 += 48) {
    float4 a_ld[6], w_ld[3];
#pragma unroll
    for (int p = 0; p < 6; ++p) {
      int f = tid + p * 256;
      int m = f / 12, c4 = (f % 12) * 4;
      a_ld[p] = *(const float4*)&A[(size_t)(bm + m) * K + k0 + c4];
    }
#pragma unroll
    for (int p = 0; p < 3; ++p) {
      int f = tid + p * 256;
      int kr = f >> 4, n4 = (f & 15) * 4;
      if (bn + n4 < N) w_ld[p] = *(const float4*)&W[(size_t)(k0 + kr) * N + bn + n4];
      else w_ld[p] = make_float4(0.f, 0.f, 0.f, 0.f);
    }
    __syncthreads();
#pragma unroll
    for (int p = 0; p < 6; ++p) {
      int f = tid + p * 256;
      int m = f / 12, c4 = (f % 12) * 4;
      As[c4 + 0][m] = a_ld[p].x; As[c4 + 1][m] = a_ld[p].y;
      As[c4 + 2][m] = a_ld[p].z; As[c4 + 3][m] = a_ld[p].w;
    }
#pragma unroll
    for (int p = 0; p < 3; ++p) {
      int f = tid + p * 256;
      int kr = f >> 4, n4 = (f & 15) * 4;
      *(float4*)&Ws[kr][n4] = w_ld[p];
    }
    __syncthreads();
#pragma unroll 8
    for (int k = 0; k < 48; ++k) {
      float4 a0 = *(const float4*)&As[k][tm2];
      float4 a1 = *(const float4*)&As[k][tm2 + 64];
      float4 wv = *(const float4*)&Ws[k][tn];
      float aa[8] = {a0.x, a0.y, a0.z, a0.w, a1.x, a1.y, a1.z, a1.w};
      float ww[4] = {wv.x, wv.y, wv.z, wv.w};
#pragma unroll
      for (int i = 0; i < 8; ++i)
#pragma unroll
        for (int j = 0; j < 4; ++j) acc[i][j] += aa[i] * ww[j];
    }
  }
#pragma unroll
  for (int i = 0; i < 8; ++i) {
    int row = bm + ((i < 4) ? (tm2 + i) : (64 + tm2 + i - 4));
#pragma unroll
    for (int j = 0; j < 4; ++j) {
      int n = bn + tn + j;
      if (n < N) C[(size_t)row * N + n] = acc[i][j];
    }
  }
}

// ---------------- bf16 MFMA GEMM, multi-mode epilogue ----------------------------
// MODE 1: A bf16, C fp32 +=   (final window output projection)
// MODE 2: A fp32->bf16, per-head q layout [bh][S][40], col33=1.0, 34..39=0
// MODE 3: same, k layout, col33 = mask bias, 34..39=0
// MODE 4: same, v TRANSPOSED layout [bh][40][S], row33=1.0, 34..39=0
template<int MODE>
__global__ __launch_bounds__(256) void gemm_bf16(const void* __restrict__ Ap,
                                                 const ushort* __restrict__ Bt,
                                                 void* __restrict__ Cp,
                                                 const int* __restrict__ maskp,
                                                 int M, int N, int K, int S) {
  __shared__ ushort As[64][40];
  __shared__ ushort Bs[64][40];
  const int bm = blockIdx.x * 64, bn = blockIdx.y * 64;
  const int tid = threadIdx.x;
  const int lane = tid & 63, w = tid >> 6;
  const int lo = lane & 15, hi = lane >> 4;
  const int row_s = tid >> 2, ch = tid & 3;
  f32x4 acc[4];
#pragma unroll
  for (int mb = 0; mb < 4; ++mb) acc[mb] = (f32x4){0.f, 0.f, 0.f, 0.f};
  const short8 zv = {0, 0, 0, 0, 0, 0, 0, 0};

  for (int k0 = 0; k0 < K; k0 += 32) {
    short8 av = zv, bv = zv;
    if (k0 + ch * 8 < K) {
      if (MODE >= 2) {
        const float* Af = (const float*)Ap;
        float4 f0 = *(const float4*)&Af[(size_t)(bm + row_s) * K + k0 + ch * 8];
        float4 f1 = *(const float4*)&Af[(size_t)(bm + row_s) * K + k0 + ch * 8 + 4];
        av[0] = (short)f2bf(f0.x); av[1] = (short)f2bf(f0.y);
        av[2] = (short)f2bf(f0.z); av[3] = (short)f2bf(f0.w);
        av[4] = (short)f2bf(f1.x); av[5] = (short)f2bf(f1.y);
        av[6] = (short)f2bf(f1.z); av[7] = (short)f2bf(f1.w);
      } else {
        av = *(const short8*)&((const ushort*)Ap)[(size_t)(bm + row_s) * K + k0 + ch * 8];
      }
      if (bn + row_s < N) bv = *(const short8*)&Bt[(size_t)(bn + row_s) * K + k0 + ch * 8];
    }
    __syncthreads();
    *(short8*)&As[row_s][ch * 8] = av;
    *(short8*)&Bs[row_s][ch * 8] = bv;
    __syncthreads();
    short8 bf = *(const short8*)&Bs[16 * w + lo][8 * hi];
#pragma unroll
    for (int mb = 0; mb < 4; ++mb) {
      short8 af = *(const short8*)&As[16 * mb + lo][8 * hi];
      acc[mb] = __builtin_amdgcn_mfma_f32_16x16x32_bf16(af, bf, acc[mb], 0, 0, 0);
    }
  }

  const int col = bn + 16 * w + lo;
  if (col < N) {
    if (MODE == 1) {
      float* Cf = (float*)Cp;
#pragma unroll
      for (int mb = 0; mb < 4; ++mb)
#pragma unroll
        for (int r = 0; r < 4; ++r)
          Cf[(size_t)(bm + 16 * mb + 4 * hi + r) * N + col] += acc[mb][r];
    } else {
      uint h = ((uint)col * 993u) >> 15;
      int e = col - (int)h * 33;
      ushort* dst = (ushort*)Cp;
#pragma unroll
      for (int mb = 0; mb < 4; ++mb)
#pragma unroll
        for (int r = 0; r < 4; ++r) {
          int row = bm + 16 * mb + 4 * hi + r;
          int b = (row >= S) ? 1 : 0;
          int nn = row - b * S;
          if (MODE == 4) {
            size_t tb = (size_t)(b * NH + (int)h) * 40;
            dst[(tb + e) * S + nn] = f2bf(acc[mb][r]);
            if (e == 0) {
              dst[(tb + 33) * S + nn] = 0x3F80;
              for (int z = 34; z < 40; ++z) dst[(tb + z) * S + nn] = 0;
            }
          } else {
            size_t base = ((size_t)(b * NH + (int)h) * S + nn) * 40;
            dst[base + e] = f2bf(acc[mb][r]);
            if (e == 0) {
              ushort pad33;
              if (MODE == 2) pad33 = 0x3F80;
              else pad33 = maskp[row] ? (ushort)0 : f2bf(-1e30f);
              dst[base + 33] = pad33;
              for (int z = 34; z < 40; ++z) dst[base + z] = 0;
            }
          }
        }
    }
  }
}

// ---------------- linear attention: partial kv over S-chunks ---------------------
// kv'[33 feat rows][36 cols]: cols 0..32 = sum ke*v, col 33 = sum ke (ksum)
__global__ __launch_bounds__(256) void lin_kv_part(const float* __restrict__ qk,
                                                   const float* __restrict__ v_lin,
                                                   float* __restrict__ kvp,
                                                   int B, int S) {
  const int bh = blockIdx.x, chunk = blockIdx.y;
  const int b = bh >> 4, h = bh & 15;
  const int tid = threadIdx.x;
  __shared__ float kraw[64][17];
  __shared__ float vsh[64][36];
  if (tid < 64) { vsh[tid][33] = 1.f; vsh[tid][34] = 0.f; vsh[tid][35] = 0.f; }
  f32x4 acc0 = {0.f, 0.f, 0.f, 0.f}, acc1 = {0.f, 0.f, 0.f, 0.f};
  const int d0 = tid / 9, c40 = (tid % 9) * 4;
  const int idx1 = tid + 256;
  const int d1 = idx1 / 9, c41 = (idx1 % 9) * 4;
  const int SC = S / 8;
  const int nbeg = chunk * SC;
  __syncthreads();
  for (int n0 = nbeg; n0 < nbeg + SC; n0 += 64) {
    {
      int row = tid >> 2, f4 = (tid & 3) * 4;
      float4 kv4 = *(const float4*)&qk[(size_t)(b * S + n0 + row) * 512 + 256 + h * 16 + f4];
      kraw[row][f4 + 0] = kv4.x; kraw[row][f4 + 1] = kv4.y;
      kraw[row][f4 + 2] = kv4.z; kraw[row][f4 + 3] = kv4.w;
    }
    for (int i = tid; i < 64 * 33; i += 256) {
      int n = i / 33, e = i - n * 33;
      vsh[n][e] = v_lin[(size_t)(b * S + n0 + n) * DM + h * HD + e];
    }
    __syncthreads();
#pragma unroll 4
    for (int n = 0; n < 64; ++n) {
      {
        float ke;
        if (d0 == 0) ke = 1.f;
        else if (d0 < 17) ke = kraw[n][d0 - 1];
        else { float kk = kraw[n][d0 - 17]; ke = 0.5f * kk * kk; }
        f32x4 v = *(const f32x4*)&vsh[n][c40];
        acc0 += ke * v;
      }
      if (idx1 < 297) {
        float ke;
        if (d1 < 17) ke = kraw[n][d1 - 1];
        else { float kk = kraw[n][d1 - 17]; ke = 0.5f * kk * kk; }
        f32x4 v = *(const f32x4*)&vsh[n][c41];
        acc1 += ke * v;
      }
    }
    __syncthreads();
  }
  float* dst = kvp + (size_t)(bh * 8 + chunk) * 1188;
  *(f32x4*)&dst[d0 * 36 + c40] = acc0;
  if (idx1 < 297) *(f32x4*)&dst[d1 * 36 + c41] = acc1;
}

__global__ __launch_bounds__(256) void lin_red(const float* __restrict__ kvp,
                                               float* __restrict__ kvr) {
  int bh = blockIdx.x;
  for (int i = threadIdx.x; i < 1188; i += 256) {
    float s = 0.f;
#pragma unroll
    for (int c = 0; c < 8; ++c) s += kvp[(size_t)(bh * 8 + c) * 1188 + i];
    kvr[(size_t)bh * 1188 + i] = s;
  }
}

// ---------------- linear attention output ---------------------------------------
__global__ __launch_bounds__(256) void lin_out_k(const float* __restrict__ qk,
                                                 const float* __restrict__ kvr,
                                                 const int* __restrict__ mask,
                                                 float* __restrict__ lin_pre,
                                                 int B, int S) {
  const int bs = blockIdx.x;
  const int b = (bs >= S) ? 1 : 0;
  __shared__ float qsh[NH][17];
  for (int i = threadIdx.x; i < NH * FEAT; i += 256)
    qsh[i >> 4][i & 15] = qk[(size_t)bs * 512 + i];
  __syncthreads();
  const int msk = mask[bs];
  for (int o = threadIdx.x; o < DM; o += 256) {
    uint h = ((uint)o * 993u) >> 15;
    int e = o - (int)h * 33;
    const float* kvh = kvr + (size_t)(b * NH + (int)h) * 1188;
    float qsum = 1.f, qkv = kvh[e];
#pragma unroll
    for (int f = 0; f < FEAT; ++f) {
      float q = qsh[h][f];
      float q2 = 0.5f * q * q;
      qsum += q + q2;
      qkv += q * kvh[(1 + f) * 36 + e] + q2 * kvh[(17 + f) * 36 + e];
    }
    float z = qsum * kvh[e * 36 + 33];
    float outv = qkv / (z + EPSF);
    if (msk == 0) outv = 0.f;
    lin_pre[(size_t)bs * DM + o] = outv;
  }
}

// ---------------- banded attention: split-K, static-max flash --------------------
__global__ __launch_bounds__(256) void win_attn_split(const ushort* __restrict__ qwb,
                                                      const ushort* __restrict__ kwb,
                                                      const ushort* __restrict__ vwbT,
                                                      ushort* __restrict__ Opart,
                                                      int S, int NT) {
  const int qt = gridDim.x - 1 - blockIdx.x;
  const int bh = blockIdx.y;
  const int part = blockIdx.z;
  const int T = min(NT, qt + 2);
  const int t0 = part * 16;
  if (t0 >= T) return;
  const int t1 = min(t0 + 16, T);
  const int n0 = qt * 64;
  const int tid = threadIdx.x;
  const int lane = tid & 63, w = tid >> 6;
  const int lo = lane & 15, hi = lane >> 4;

  __shared__ ushort Ks[64][72];
  __shared__ ushort Vt[48][72];
  __shared__ ushort Ps[4][16][72];
  for (int i = tid; i < 64 * 72; i += 256) ((ushort*)Ks)[i] = 0;
  for (int i = tid; i < 48 * 72; i += 256) ((ushort*)Vt)[i] = 0;

  const ushort* qrow = qwb + ((size_t)bh * S + n0 + w * 16 + lo) * 40;
  short8 qf0 = *(const short8*)&qrow[8 * hi];
  short8 qf1 = (hi == 0) ? *(const short8*)&qrow[32] : (short8){0, 0, 0, 0, 0, 0, 0, 0};

  f32x4 Oacc[3];
#pragma unroll
  for (int eb = 0; eb < 3; ++eb) Oacc[eb] = (f32x4){0.f, 0.f, 0.f, 0.f};
  __syncthreads();

  for (int t = t0; t < t1; ++t) {
    const int m0 = t * 64;
    for (int c = tid; c < 320; c += 256) {
      int row = c / 5, cc = c % 5;
      *(short8*)&Ks[row][cc * 8] =
          *(const short8*)&kwb[((size_t)bh * S + m0 + row) * 40 + cc * 8];
    }
    for (int c = tid; c < 320; c += 256) {
      int e = c >> 3, cc = c & 7;
      *(short8*)&Vt[e][cc * 8] =
          *(const short8*)&vwbT[((size_t)bh * 40 + e) * S + m0 + cc * 8];
    }
    __syncthreads();

    f32x4 accS[4];
#pragma unroll
    for (int bb = 0; bb < 4; ++bb) accS[bb] = (f32x4){0.f, 0.f, 0.f, 0.f};
#pragma unroll
    for (int bb = 0; bb < 4; ++bb) {
      short8 kf0 = *(const short8*)&Ks[16 * bb + lo][8 * hi];
      short8 kf1 = *(const short8*)&Ks[16 * bb + lo][32 + 8 * hi];
      accS[bb] = __builtin_amdgcn_mfma_f32_16x16x32_bf16(qf0, kf0, accS[bb], 0, 0, 0);
      accS[bb] = __builtin_amdgcn_mfma_f32_16x16x32_bf16(qf1, kf1, accS[bb], 0, 0, 0);
    }

    const bool boundary = (m0 > n0);
    float pvv[4][4];
#pragma unroll
    for (int bb = 0; bb < 4; ++bb)
#pragma unroll
      for (int r = 0; r < 4; ++r) {
        float p = exp2f(fmaf(accS[bb][r], K1C, -K2C));
        if (boundary && (16 * bb + lo) >= (4 * hi + r)) p = 0.f;
        pvv[bb][r] = p;
      }
#pragma unroll
    for (int r = 0; r < 4; ++r)
#pragma unroll
      for (int bb = 0; bb < 4; ++bb)
        Ps[w][4 * hi + r][16 * bb + lo] = f2bf(pvv[bb][r]);

    short8 pf0 = *(const short8*)&Ps[w][lo][8 * hi];
    short8 pf1 = *(const short8*)&Ps[w][lo][32 + 8 * hi];
#pragma unroll
    for (int eb = 0; eb < 3; ++eb) {
      short8 vf0 = *(const short8*)&Vt[16 * eb + lo][8 * hi];
      short8 vf1 = *(const short8*)&Vt[16 * eb + lo][32 + 8 * hi];
      Oacc[eb] = __builtin_amdgcn_mfma_f32_16x16x32_bf16(pf0, vf0, Oacc[eb], 0, 0, 0);
      Oacc[eb] = __builtin_amdgcn_mfma_f32_16x16x32_bf16(pf1, vf1, Oacc[eb], 0, 0, 0);
    }
    __syncthreads();
  }

  const size_t ob = ((size_t)(bh * NT + qt) * 2 + part) * 2560;
#pragma unroll
  for (int eb = 0; eb < 3; ++eb) {
    int e = 16 * eb + lo;
    if (e < 40) {
#pragma unroll
      for (int r = 0; r < 4; ++r)
        Opart[ob + (w * 16 + 4 * hi + r) * 40 + e] = f2bf(Oacc[eb][r]);
    }
  }
}

// ---------------- combine partials -> wpb [M][528] bf16 --------------------------
__global__ __launch_bounds__(256) void win_combine(const ushort* __restrict__ Opart,
                                                   ushort* __restrict__ wpb,
                                                   int S, int NT) {
  const int qt = blockIdx.x, bh = blockIdx.y;
  const int b = bh >> 4, h = bh & 15;
  const int T = min(NT, qt + 2);
  const int P = (T + 15) >> 4;
  const size_t base = ((size_t)(bh * NT + qt) * 2) * 2560;
  __shared__ float linv[64];
  const int tid = threadIdx.x;
  if (tid < 64) {
    float l = bf2f(Opart[base + tid * 40 + 33]);
    if (P > 1) l += bf2f(Opart[base + 2560 + tid * 40 + 33]);
    linv[tid] = (l > 0.f) ? 1.f / l : 0.f;
  }
  __syncthreads();
  for (int i = tid; i < 64 * 33; i += 256) {
    int row = i / 33, e = i - row * 33;
    float o = bf2f(Opart[base + row * 40 + e]);
    if (P > 1) o += bf2f(Opart[base + 2560 + row * 40 + e]);
    int n = qt * 64 + row;
    wpb[((size_t)(b * S + n)) * DM + h * HD + e] = f2bf(o * linv[row]);
  }
}

extern "C" void kernel_launch(void* const* d_in, const int* in_sizes, int n_in,
                              void* d_out, int out_size, void* d_ws, size_t ws_size,
                              hipStream_t stream) {
  const float* x      = (const float*)d_in[0];
  const int*   mask   = (const int*)d_in[1];
  const float* Wq_lin = (const float*)d_in[2];
  const float* Wk_lin = (const float*)d_in[3];
  const float* Wv_lin = (const float*)d_in[4];
  const float* Wo_lin = (const float*)d_in[5];
  const float* Wq_win = (const float*)d_in[6];
  const float* Wk_win = (const float*)d_in[7];
  const float* Wv_win = (const float*)d_in[8];
  const float* Wo_win = (const float*)d_in[9];
  float* out = (float*)d_out;

  const int BS = in_sizes[1];
  const int B = 2;
  const int S = BS / B;
  const int NT = S / 64;
  const int M = BS, K = DM;

  // fp32 workspace
  float* ws = (float*)d_ws;
  float* Wqk     = ws;  ws += (size_t)DM * 512;
  float* qk      = ws;  ws += (size_t)BS * 512;
  float* v_lin   = ws;  ws += (size_t)BS * DM;
  float* lin_pre = ws;  ws += (size_t)BS * DM;
  float* kvp     = ws;  ws += (size_t)B * NH * 8 * 1188;
  float* kvr     = ws;  ws += (size_t)B * NH * 1188;
  // bf16 workspace
  ushort* ub   = (ushort*)ws;
  ushort* qwb  = ub;  ub += (size_t)B * NH * S * 40;
  ushort* kwb  = ub;  ub += (size_t)B * NH * S * 40;
  ushort* vwbT = ub;  ub += (size_t)B * NH * 40 * S;
  ushort* wpb  = ub;  ub += (size_t)BS * DM;
  ushort* WqT  = ub;  ub += (size_t)DM * DM;
  ushort* WkT  = ub;  ub += (size_t)DM * DM;
  ushort* WvT  = ub;  ub += (size_t)DM * DM;
  ushort* WoT  = ub;  ub += (size_t)DM * DM;
  ushort* Opart = ub; ub += (size_t)B * NH * NT * 2 * 2560;

  dim3 blk(256);
  dim3 gt((DM + 31) / 32, (DM + 31) / 32);

  // weight prep
  wt_cvt<<<gt, blk, 0, stream>>>(Wq_win, WqT, DM, DM);
  wt_cvt<<<gt, blk, 0, stream>>>(Wk_win, WkT, DM, DM);
  wt_cvt<<<gt, blk, 0, stream>>>(Wv_win, WvT, DM, DM);
  wt_cvt<<<gt, blk, 0, stream>>>(Wo_win, WoT, DM, DM);
  pack_qk<<<(DM * 512 + 255) / 256, blk, 0, stream>>>(Wq_lin, Wk_lin, Wqk);

  // linear path projections (fp32)
  gemm_f32<<<dim3(M / 128, 8), blk, 0, stream>>>(x, Wqk, qk, M, 512, K);
  gemm_f32<<<dim3(M / 128, 9), blk, 0, stream>>>(x, Wv_lin, v_lin, M, DM, K);

  // window path projections (bf16, per-head layouts)
  gemm_bf16<2><<<dim3(M / 64, 9), blk, 0, stream>>>(x, WqT, qwb, nullptr, M, DM, K, S);
  gemm_bf16<3><<<dim3(M / 64, 9), blk, 0, stream>>>(x, WkT, kwb, mask, M, DM, K, S);
  gemm_bf16<4><<<dim3(M / 64, 9), blk, 0, stream>>>(x, WvT, vwbT, nullptr, M, DM, K, S);

  // linear attention
  lin_kv_part<<<dim3(B * NH, 8), blk, 0, stream>>>(qk, v_lin, kvp, B, S);
  lin_red<<<dim3(B * NH), blk, 0, stream>>>(kvp, kvr);
  lin_out_k<<<dim3(BS), blk, 0, stream>>>(qk, kvr, mask, lin_pre, B, S);

  // banded attention (split-K + combine)
  win_attn_split<<<dim3(NT, B * NH, 2), blk, 0, stream>>>(qwb, kwb, vwbT, Opart, S, NT);
  win_combine<<<dim3(NT, B * NH), blk, 0, stream>>>(Opart, wpb, S, NT);

  // output projections
  gemm_f32<<<dim3(M / 128, 9), blk, 0, stream>>>(lin_pre, Wo_lin, out, M, DM, K);
  gemm_bf16<1><<<dim3(M / 64, 9), blk, 0, stream>>>(wpb, WoT, out, nullptr, M, DM, K, S);
}

// Round 5
// 296.678 us; speedup vs baseline: 9.6470x; 1.4216x over previous
//
#include <hip/hip_runtime.h>

#define NH 16
#define FEAT 16
#define HD 33
#define DM 528
#define WIN 64
#define EPSF 1e-9f
#define K1C (0.17407765595569785f * 1.4426950408889634f)
#define K2C (4.0f * 1.4426950408889634f)
#define KP 544               // padded K for projections
#define NWIN 1584            // 528 q + 528 k + 528 v
#define KOUT 1056            // 528 lin + 528 win

typedef float f32x4 __attribute__((ext_vector_type(4)));
typedef short short8 __attribute__((ext_vector_type(8)));

__device__ inline ushort f2bf(float f) {
  uint u = __float_as_uint(f);
  uint r = u + 0x7fffu + ((u >> 16) & 1u);
  return (ushort)(r >> 16);
}
__device__ inline float bf2f(ushort u) { return __uint_as_float(((uint)u) << 16); }

// ---------------- x fp32 [M][528] -> bf16 [M][544] zero-padded -------------------
__global__ __launch_bounds__(256) void x_cvt(const float* __restrict__ x,
                                             ushort* __restrict__ xb, int M) {
  int total = M * KP;
  for (int i = blockIdx.x * 256 + threadIdx.x; i < total; i += gridDim.x * 256) {
    int row = i / KP, c = i - row * KP;
    xb[i] = (c < DM) ? f2bf(x[(size_t)row * DM + c]) : (ushort)0;
  }
}

// ---------------- pack Wq_lin | Wk_lin -> Wqk [528][512] fp32 --------------------
__global__ __launch_bounds__(256) void pack_qk(const float* __restrict__ Wq,
                                               const float* __restrict__ Wk,
                                               float* __restrict__ Wqk) {
  int i = blockIdx.x * 256 + threadIdx.x;
  if (i < DM * 512) {
    int k = i >> 9, n = i & 511;
    Wqk[i] = (n < 256) ? Wq[k * 256 + n] : Wk[k * 256 + n - 256];
  }
}

// ---------------- Wv_lin [528][528] -> bf16 T [528][544] -------------------------
__global__ __launch_bounds__(256) void pack_v(const float* __restrict__ Wv,
                                              ushort* __restrict__ dst) {
  int total = DM * KP;
  for (int i = blockIdx.x * 256 + threadIdx.x; i < total; i += gridDim.x * 256) {
    int n = i / KP, k = i - n * KP;
    dst[i] = (k < DM) ? f2bf(Wv[(size_t)k * DM + n]) : (ushort)0;
  }
}

__global__ __launch_bounds__(256) void pack_win(const float* __restrict__ Wq,
                                                const float* __restrict__ Wk,
                                                const float* __restrict__ Wv,
                                                ushort* __restrict__ dst) {
  int total = NWIN * KP;
  for (int i = blockIdx.x * 256 + threadIdx.x; i < total; i += gridDim.x * 256) {
    int n = i / KP, k = i - n * KP;
    float v = 0.f;
    if (k < DM) {
      if (n < DM) v = Wq[(size_t)k * DM + n];
      else if (n < 2 * DM) v = Wk[(size_t)k * DM + (n - DM)];
      else v = Wv[(size_t)k * DM + (n - 2 * DM)];
    }
    dst[i] = f2bf(v);
  }
}

__global__ __launch_bounds__(256) void pack_out(const float* __restrict__ Wo_lin,
                                                const float* __restrict__ Wo_win,
                                                ushort* __restrict__ dst) {
  int total = DM * KOUT;
  for (int i = blockIdx.x * 256 + threadIdx.x; i < total; i += gridDim.x * 256) {
    int n = i / KOUT, k = i - n * KOUT;
    float v = (k < DM) ? Wo_lin[(size_t)k * DM + n] : Wo_win[(size_t)(k - DM) * DM + n];
    dst[i] = f2bf(v);
  }
}

// ---------------- fp32 GEMM: C[M,N] = A[M,K] @ W[K,N]; 128x64, BK=48 -------------
__global__ __launch_bounds__(256) void gemm_f32(const float* __restrict__ A,
                                                const float* __restrict__ W,
                                                float* __restrict__ C,
                                                int M, int N, int K) {
  __shared__ float As[48][132];
  __shared__ float Ws[48][72];
  const int bm = blockIdx.x * 128, bn = blockIdx.y * 64;
  const int tid = threadIdx.x;
  const int tm2 = (tid >> 4) * 4, tn = (tid & 15) * 4;
  float acc[8][4] = {};
  for (int k0 = 0; k0 < K; k0 += 48) {
    float4 a_ld[6], w_ld[3];
#pragma unroll
    for (int p = 0; p < 6; ++p) {
      int f = tid + p * 256;
      int m = f / 12, c4 = (f % 12) * 4;
      a_ld[p] = *(const float4*)&A[(size_t)(bm + m) * K + k0 + c4];
    }
#pragma unroll
    for (int p = 0; p < 3; ++p) {
      int f = tid + p * 256;
      int kr = f >> 4, n4 = (f & 15) * 4;
      if (bn + n4 < N) w_ld[p] = *(const float4*)&W[(size_t)(k0 + kr) * N + bn + n4];
      else w_ld[p] = make_float4(0.f, 0.f, 0.f, 0.f);
    }
    __syncthreads();
#pragma unroll
    for (int p = 0; p < 6; ++p) {
      int f = tid + p * 256;
      int m = f / 12, c4 = (f % 12) * 4;
      As[c4 + 0][m] = a_ld[p].x; As[c4 + 1][m] = a_ld[p].y;
      As[c4 + 2][m] = a_ld[p].z; As[c4 + 3][m] = a_ld[p].w;
    }
#pragma unroll
    for (int p = 0; p < 3; ++p) {
      int f = tid + p * 256;
      int kr = f >> 4, n4 = (f & 15) * 4;
      *(float4*)&Ws[kr][n4] = w_ld[p];
    }
    __syncthreads();
#pragma unroll 8
    for (int k = 0; k < 48; ++k) {
      float4 a0 = *(const float4*)&As[k][tm2];
      float4 a1 = *(const float4*)&As[k][tm2 + 64];
      float4 wv = *(const float4*)&Ws[k][tn];
      float aa[8] = {a0.x, a0.y, a0.z, a0.w, a1.x, a1.y, a1.z, a1.w};
      float ww[4] = {wv.x, wv.y, wv.z, wv.w};
#pragma unroll
      for (int i = 0; i < 8; ++i)
#pragma unroll
        for (int j = 0; j < 4; ++j) acc[i][j] += aa[i] * ww[j];
    }
  }
#pragma unroll
  for (int i = 0; i < 8; ++i) {
    int row = bm + ((i < 4) ? (tm2 + i) : (64 + tm2 + i - 4));
#pragma unroll
    for (int j = 0; j < 4; ++j) {
      int n = bn + tn + j;
      if (n < N) C[(size_t)row * N + n] = acc[i][j];
    }
  }
}

// ---------------- bf16 MFMA GEMM 128x128, 4 waves --------------------------------
// MODE 0: win proj -> per-head bf16 layouts (q [bh][S][40] | k +maskbias | vT [bh][40][S])
// MODE 1: v_lin    -> fp32 store [M][528]
// MODE 2: out      -> fp32 direct store [M][528]
template<int MODE>
__global__ __launch_bounds__(256) void gemm_mfma(const ushort* __restrict__ A,
                                                 const ushort* __restrict__ Bt,
                                                 void* __restrict__ C0,
                                                 const int* __restrict__ maskp,
                                                 int Nvalid, int Kp, int S) {
  __shared__ ushort As[128][36];
  __shared__ ushort Bs[128][36];
  const int bm = blockIdx.x * 128, bn = blockIdx.y * 128;
  const int tid = threadIdx.x;
  const int lane = tid & 63, w = tid >> 6;
  const int lo = lane & 15, hi = lane >> 4;
  const int wr = w >> 1, wc = w & 1;
  f32x4 acc[4][4];
#pragma unroll
  for (int mb = 0; mb < 4; ++mb)
#pragma unroll
    for (int nb = 0; nb < 4; ++nb) acc[mb][nb] = (f32x4){0.f, 0.f, 0.f, 0.f};
  const short8 zv = {0, 0, 0, 0, 0, 0, 0, 0};

  for (int k0 = 0; k0 < Kp; k0 += 32) {
    short8 a_ld[2], b_ld[2];
#pragma unroll
    for (int p = 0; p < 2; ++p) {
      int c = tid + p * 256;
      int row = c >> 2, cc = c & 3;
      a_ld[p] = *(const short8*)&A[(size_t)(bm + row) * Kp + k0 + cc * 8];
      int bnr = bn + row;
      b_ld[p] = (bnr < Nvalid) ? *(const short8*)&Bt[(size_t)bnr * Kp + k0 + cc * 8] : zv;
    }
    __syncthreads();
#pragma unroll
    for (int p = 0; p < 2; ++p) {
      int c = tid + p * 256;
      int row = c >> 2, cc = c & 3;
      *(short8*)&As[row][cc * 8] = a_ld[p];
      *(short8*)&Bs[row][cc * 8] = b_ld[p];
    }
    __syncthreads();
    short8 afr[4], bfr[4];
#pragma unroll
    for (int mb = 0; mb < 4; ++mb) afr[mb] = *(const short8*)&As[wr * 64 + 16 * mb + lo][8 * hi];
#pragma unroll
    for (int nb = 0; nb < 4; ++nb) bfr[nb] = *(const short8*)&Bs[wc * 64 + 16 * nb + lo][8 * hi];
#pragma unroll
    for (int mb = 0; mb < 4; ++mb)
#pragma unroll
      for (int nb = 0; nb < 4; ++nb)
        acc[mb][nb] = __builtin_amdgcn_mfma_f32_16x16x32_bf16(afr[mb], bfr[nb], acc[mb][nb], 0, 0, 0);
  }

#pragma unroll
  for (int nb = 0; nb < 4; ++nb) {
    const int col = bn + wc * 64 + 16 * nb + lo;
    if (col >= Nvalid) continue;
    if (MODE == 1 || MODE == 2) {
      float* Cf = (float*)C0;
#pragma unroll
      for (int mb = 0; mb < 4; ++mb)
#pragma unroll
        for (int r = 0; r < 4; ++r) {
          int row = bm + wr * 64 + 16 * mb + 4 * hi + r;
          Cf[(size_t)row * DM + col] = acc[mb][nb][r];
        }
    } else {
      const int seg = col / DM;          // 0=q 1=k 2=v
      const int cc = col - seg * DM;
      const uint h = ((uint)cc * 993u) >> 15;
      const int e = cc - (int)h * 33;
      ushort* dst = (ushort*)C0 + (size_t)seg * (32u * (uint)S * 40u);
#pragma unroll
      for (int mb = 0; mb < 4; ++mb)
#pragma unroll
        for (int r = 0; r < 4; ++r) {
          int row = bm + wr * 64 + 16 * mb + 4 * hi + r;
          int b = (row >= S) ? 1 : 0;
          int nn = row - b * S;
          float val = acc[mb][nb][r];
          if (seg == 2) {
            size_t tb = (size_t)(b * NH + (int)h) * 40;
            dst[(tb + e) * S + nn] = f2bf(val);
            if (e == 0) {
              dst[(tb + 33) * S + nn] = 0x3F80;
#pragma unroll
              for (int z = 34; z < 40; ++z) dst[(tb + z) * S + nn] = 0;
            }
          } else {
            size_t base = ((size_t)(b * NH + (int)h) * S + nn) * 40;
            dst[base + e] = f2bf(val);
            if (e == 0) {
              ushort pad33 = (seg == 0) ? (ushort)0x3F80
                                        : (maskp[row] ? (ushort)0 : f2bf(-1e30f));
              dst[base + 33] = pad33;
#pragma unroll
              for (int z = 34; z < 40; ++z) dst[base + z] = 0;
            }
          }
        }
    }
  }
}

// ---------------- linear attention: partial kv over S-chunks ---------------------
__global__ __launch_bounds__(256) void lin_kv_part(const float* __restrict__ qk,
                                                   const float* __restrict__ v_lin,
                                                   float* __restrict__ kvp,
                                                   int B, int S) {
  const int bh = blockIdx.x, chunk = blockIdx.y;
  const int b = bh >> 4, h = bh & 15;
  const int tid = threadIdx.x;
  __shared__ float kraw[64][17];
  __shared__ float vsh[64][36];
  if (tid < 64) { vsh[tid][33] = 1.f; vsh[tid][34] = 0.f; vsh[tid][35] = 0.f; }
  f32x4 acc0 = {0.f, 0.f, 0.f, 0.f}, acc1 = {0.f, 0.f, 0.f, 0.f};
  const int d0 = tid / 9, c40 = (tid % 9) * 4;
  const int idx1 = tid + 256;
  const int d1 = idx1 / 9, c41 = (idx1 % 9) * 4;
  const int SC = S / 8;
  const int nbeg = chunk * SC;
  __syncthreads();
  for (int n0 = nbeg; n0 < nbeg + SC; n0 += 64) {
    {
      int row = tid >> 2, f4 = (tid & 3) * 4;
      float4 kv4 = *(const float4*)&qk[(size_t)(b * S + n0 + row) * 512 + 256 + h * 16 + f4];
      kraw[row][f4 + 0] = kv4.x; kraw[row][f4 + 1] = kv4.y;
      kraw[row][f4 + 2] = kv4.z; kraw[row][f4 + 3] = kv4.w;
    }
    for (int i = tid; i < 64 * 33; i += 256) {
      int n = i / 33, e = i - n * 33;
      vsh[n][e] = v_lin[(size_t)(b * S + n0 + n) * DM + h * HD + e];
    }
    __syncthreads();
#pragma unroll 4
    for (int n = 0; n < 64; ++n) {
      {
        float ke;
        if (d0 == 0) ke = 1.f;
        else if (d0 < 17) ke = kraw[n][d0 - 1];
        else { float kk = kraw[n][d0 - 17]; ke = 0.5f * kk * kk; }
        f32x4 v = *(const f32x4*)&vsh[n][c40];
        acc0 += ke * v;
      }
      if (idx1 < 297) {
        float ke;
        if (d1 < 17) ke = kraw[n][d1 - 1];
        else { float kk = kraw[n][d1 - 17]; ke = 0.5f * kk * kk; }
        f32x4 v = *(const f32x4*)&vsh[n][c41];
        acc1 += ke * v;
      }
    }
    __syncthreads();
  }
  float* dst = kvp + (size_t)(bh * 8 + chunk) * 1188;
  *(f32x4*)&dst[d0 * 36 + c40] = acc0;
  if (idx1 < 297) *(f32x4*)&dst[d1 * 36 + c41] = acc1;
}

__global__ __launch_bounds__(256) void lin_red(const float* __restrict__ kvp,
                                               float* __restrict__ kvr) {
  int bh = blockIdx.x;
  for (int i = threadIdx.x; i < 1188; i += 256) {
    float s = 0.f;
#pragma unroll
    for (int c = 0; c < 8; ++c) s += kvp[(size_t)(bh * 8 + c) * 1188 + i];
    kvr[(size_t)bh * 1188 + i] = s;
  }
}

// ---------------- linear attention output -> cat[:, 0:528] bf16 ------------------
__global__ __launch_bounds__(256) void lin_out_k(const float* __restrict__ qk,
                                                 const float* __restrict__ kvr,
                                                 const int* __restrict__ mask,
                                                 ushort* __restrict__ cat,
                                                 int B, int S) {
  const int bs = blockIdx.x;
  const int b = (bs >= S) ? 1 : 0;
  __shared__ float qsh[NH][17];
  for (int i = threadIdx.x; i < NH * FEAT; i += 256)
    qsh[i >> 4][i & 15] = qk[(size_t)bs * 512 + i];
  __syncthreads();
  const int msk = mask[bs];
  for (int o = threadIdx.x; o < DM; o += 256) {
    uint h = ((uint)o * 993u) >> 15;
    int e = o - (int)h * 33;
    const float* kvh = kvr + (size_t)(b * NH + (int)h) * 1188;
    float qsum = 1.f, qkv = kvh[e];
#pragma unroll
    for (int f = 0; f < FEAT; ++f) {
      float q = qsh[h][f];
      float q2 = 0.5f * q * q;
      qsum += q + q2;
      qkv += q * kvh[(1 + f) * 36 + e] + q2 * kvh[(17 + f) * 36 + e];
    }
    float z = qsum * kvh[e * 36 + 33];
    float outv = qkv / (z + EPSF);
    if (msk == 0) outv = 0.f;
    cat[(size_t)bs * KOUT + o] = f2bf(outv);
  }
}

// ---------------- banded attention: QBLK=128, split-K, static-max ----------------
__global__ __launch_bounds__(256) void win_attn2(const ushort* __restrict__ qwb,
                                                 const ushort* __restrict__ kwb,
                                                 const ushort* __restrict__ vwbT,
                                                 ushort* __restrict__ Opart,
                                                 int S, int NT2) {
  const int qt = gridDim.x - 1 - blockIdx.x;
  const int bh = blockIdx.y;
  const int part = blockIdx.z;
  const int NT = NT2 * 2;
  const int T = min(NT, 2 * qt + 3);
  const int t0 = part * 16;
  if (t0 >= T) return;
  const int t1 = min(t0 + 16, T);
  const int n0 = qt * 128;
  const int tid = threadIdx.x;
  const int lane = tid & 63, w = tid >> 6;
  const int lo = lane & 15, hi = lane >> 4;

  __shared__ ushort Ks[64][72];
  __shared__ ushort Vt[48][72];
  __shared__ ushort Ps[4][32][72];
  for (int i = tid; i < 64 * 72; i += 256) ((ushort*)Ks)[i] = 0;
  for (int i = tid; i < 48 * 72; i += 256) ((ushort*)Vt)[i] = 0;

  short8 qf[2][2];
#pragma unroll
  for (int qr = 0; qr < 2; ++qr) {
    const ushort* qrow = qwb + ((size_t)bh * S + n0 + w * 32 + qr * 16 + lo) * 40;
    qf[qr][0] = *(const short8*)&qrow[8 * hi];
    qf[qr][1] = (hi == 0) ? *(const short8*)&qrow[32] : (short8){0, 0, 0, 0, 0, 0, 0, 0};
  }

  f32x4 Oacc[2][3];
#pragma unroll
  for (int qr = 0; qr < 2; ++qr)
#pragma unroll
    for (int eb = 0; eb < 3; ++eb) Oacc[qr][eb] = (f32x4){0.f, 0.f, 0.f, 0.f};
  __syncthreads();

  for (int t = t0; t < t1; ++t) {
    const int m0 = t * 64;
    for (int c = tid; c < 320; c += 256) {
      int row = c / 5, cc = c - row * 5;
      *(short8*)&Ks[row][cc * 8] =
          *(const short8*)&kwb[((size_t)bh * S + m0 + row) * 40 + cc * 8];
    }
    for (int c = tid; c < 320; c += 256) {
      int e = c >> 3, cc = c & 7;
      *(short8*)&Vt[e][cc * 8] =
          *(const short8*)&vwbT[((size_t)bh * 40 + e) * S + m0 + cc * 8];
    }
    __syncthreads();

    f32x4 accS[2][4];
#pragma unroll
    for (int qr = 0; qr < 2; ++qr)
#pragma unroll
      for (int bb = 0; bb < 4; ++bb) accS[qr][bb] = (f32x4){0.f, 0.f, 0.f, 0.f};
#pragma unroll
    for (int bb = 0; bb < 4; ++bb) {
      short8 kf0 = *(const short8*)&Ks[16 * bb + lo][8 * hi];
      short8 kf1 = *(const short8*)&Ks[16 * bb + lo][32 + 8 * hi];
#pragma unroll
      for (int qr = 0; qr < 2; ++qr) {
        accS[qr][bb] = __builtin_amdgcn_mfma_f32_16x16x32_bf16(qf[qr][0], kf0, accS[qr][bb], 0, 0, 0);
        accS[qr][bb] = __builtin_amdgcn_mfma_f32_16x16x32_bf16(qf[qr][1], kf1, accS[qr][bb], 0, 0, 0);
      }
    }

    const bool boundary = (m0 > n0);
    const int dmn = m0 - n0;
#pragma unroll
    for (int qr = 0; qr < 2; ++qr)
#pragma unroll
      for (int bb = 0; bb < 4; ++bb)
#pragma unroll
        for (int r = 0; r < 4; ++r) {
          float p = exp2f(fmaf(accS[qr][bb][r], K1C, -K2C));
          if (boundary) {
            int rr = w * 32 + qr * 16 + 4 * hi + r;
            int c = 16 * bb + lo;
            if (c > rr + 63 - dmn) p = 0.f;
          }
          Ps[w][qr * 16 + 4 * hi + r][16 * bb + lo] = f2bf(p);
        }

#pragma unroll
    for (int qr = 0; qr < 2; ++qr) {
      short8 pf0 = *(const short8*)&Ps[w][qr * 16 + lo][8 * hi];
      short8 pf1 = *(const short8*)&Ps[w][qr * 16 + lo][32 + 8 * hi];
#pragma unroll
      for (int eb = 0; eb < 3; ++eb) {
        short8 vf0 = *(const short8*)&Vt[16 * eb + lo][8 * hi];
        short8 vf1 = *(const short8*)&Vt[16 * eb + lo][32 + 8 * hi];
        Oacc[qr][eb] = __builtin_amdgcn_mfma_f32_16x16x32_bf16(pf0, vf0, Oacc[qr][eb], 0, 0, 0);
        Oacc[qr][eb] = __builtin_amdgcn_mfma_f32_16x16x32_bf16(pf1, vf1, Oacc[qr][eb], 0, 0, 0);
      }
    }
    __syncthreads();
  }

  const size_t ob = ((size_t)(bh * NT2 + qt) * 2 + part) * 5120;
#pragma unroll
  for (int qr = 0; qr < 2; ++qr)
#pragma unroll
    for (int eb = 0; eb < 3; ++eb) {
      int e = 16 * eb + lo;
      if (e < 40) {
#pragma unroll
        for (int r = 0; r < 4; ++r)
          Opart[ob + (size_t)(w * 32 + qr * 16 + 4 * hi + r) * 40 + e] = f2bf(Oacc[qr][eb][r]);
      }
    }
}

// ---------------- combine partials -> cat[:, 528:1056] bf16 ----------------------
__global__ __launch_bounds__(256) void win_combine(const ushort* __restrict__ Opart,
                                                   ushort* __restrict__ cat,
                                                   int S, int NT2) {
  const int qt = blockIdx.x, bh = blockIdx.y;
  const int b = bh >> 4, h = bh & 15;
  const int T = min(NT2 * 2, 2 * qt + 3);
  const bool P2 = (T > 16);
  const size_t base = (size_t)(bh * NT2 + qt) * 2 * 5120;
  __shared__ float linv[128];
  const int tid = threadIdx.x;
  if (tid < 128) {
    float l = bf2f(Opart[base + tid * 40 + 33]);
    if (P2) l += bf2f(Opart[base + 5120 + tid * 40 + 33]);
    linv[tid] = (l > 0.f) ? 1.f / l : 0.f;
  }
  __syncthreads();
  for (int i = tid; i < 128 * 33; i += 256) {
    int row = i / 33, e = i - row * 33;
    float o = bf2f(Opart[base + row * 40 + e]);
    if (P2) o += bf2f(Opart[base + 5120 + row * 40 + e]);
    int n = qt * 128 + row;
    cat[((size_t)(b * S + n)) * KOUT + DM + h * HD + e] = f2bf(o * linv[row]);
  }
}

extern "C" void kernel_launch(void* const* d_in, const int* in_sizes, int n_in,
                              void* d_out, int out_size, void* d_ws, size_t ws_size,
                              hipStream_t stream) {
  const float* x      = (const float*)d_in[0];
  const int*   mask   = (const int*)d_in[1];
  const float* Wq_lin = (const float*)d_in[2];
  const float* Wk_lin = (const float*)d_in[3];
  const float* Wv_lin = (const float*)d_in[4];
  const float* Wo_lin = (const float*)d_in[5];
  const float* Wq_win = (const float*)d_in[6];
  const float* Wk_win = (const float*)d_in[7];
  const float* Wv_win = (const float*)d_in[8];
  const float* Wo_win = (const float*)d_in[9];
  float* out = (float*)d_out;

  const int BS = in_sizes[1];
  const int B = 2;
  const int S = BS / B;
  const int NT2 = S / 128;
  const int M = BS;

  // fp32 workspace
  float* ws = (float*)d_ws;
  float* Wqk     = ws;  ws += (size_t)DM * 512;
  float* qk      = ws;  ws += (size_t)BS * 512;
  float* v_lin   = ws;  ws += (size_t)BS * DM;
  float* kvp     = ws;  ws += (size_t)B * NH * 8 * 1188;
  float* kvr     = ws;  ws += (size_t)B * NH * 1188;
  // bf16 workspace
  ushort* ub    = (ushort*)ws;
  ushort* x_bf  = ub;  ub += (size_t)M * KP;
  ushort* qkvw  = ub;  ub += (size_t)3 * 32 * S * 40;     // q | k | vT contiguous
  ushort* cat   = ub;  ub += (size_t)M * KOUT;
  ushort* WvT   = ub;  ub += (size_t)DM * KP;
  ushort* WwinT = ub;  ub += (size_t)NWIN * KP;
  ushort* WoT2  = ub;  ub += (size_t)DM * KOUT;
  ushort* Opart = ub;  ub += (size_t)32 * NT2 * 2 * 5120;

  ushort* qwb  = qkvw;
  ushort* kwb  = qkvw + (size_t)32 * S * 40;
  ushort* vwbT = qkvw + (size_t)64 * S * 40;

  dim3 blk(256);

  // conversions / weight packs
  x_cvt<<<2048, blk, 0, stream>>>(x, x_bf, M);
  pack_qk<<<(DM * 512 + 255) / 256, blk, 0, stream>>>(Wq_lin, Wk_lin, Wqk);
  pack_v<<<1024, blk, 0, stream>>>(Wv_lin, WvT);
  pack_win<<<1536, blk, 0, stream>>>(Wq_win, Wk_win, Wv_win, WwinT);
  pack_out<<<1024, blk, 0, stream>>>(Wo_lin, Wo_win, WoT2);

  // linear path projections: q,k in fp32 (z-sensitivity), v via bf16 MFMA
  gemm_f32<<<dim3(M / 128, 8), blk, 0, stream>>>(x, Wqk, qk, M, 512, DM);
  gemm_mfma<1><<<dim3(M / 128, (DM + 127) / 128), blk, 0, stream>>>(
      x_bf, WvT, v_lin, nullptr, DM, KP, S);

  // window path projections (bf16, per-head layouts)
  gemm_mfma<0><<<dim3(M / 128, (NWIN + 127) / 128), blk, 0, stream>>>(
      x_bf, WwinT, qkvw, mask, NWIN, KP, S);

  // linear attention (fp32 math)
  lin_kv_part<<<dim3(B * NH, 8), blk, 0, stream>>>(qk, v_lin, kvp, B, S);
  lin_red<<<dim3(B * NH), blk, 0, stream>>>(kvp, kvr);
  lin_out_k<<<dim3(BS), blk, 0, stream>>>(qk, kvr, mask, cat, B, S);

  // banded attention
  win_attn2<<<dim3(NT2, B * NH, 2), blk, 0, stream>>>(qwb, kwb, vwbT, Opart, S, NT2);
  win_combine<<<dim3(NT2, B * NH), blk, 0, stream>>>(Opart, cat, S, NT2);

  // fused output projection: out = cat @ [Wo_lin; Wo_win]
  gemm_mfma<2><<<dim3(M / 128, (DM + 127) / 128), blk, 0, stream>>>(
      cat, WoT2, out, nullptr, DM, KOUT, S);
}

// Round 6
// 282.153 us; speedup vs baseline: 10.1436x; 1.0515x over previous
//
#include <hip/hip_runtime.h>

#define NH 16
#define FEAT 16
#define HD 33
#define DM 528
#define WIN 64
#define EPSF 1e-9f
#define K1C (0.17407765595569785f * 1.4426950408889634f)
#define K2C (4.0f * 1.4426950408889634f)
#define KP 544               // padded K for projections
#define KSPLIT 1632          // 3*544 for hi/lo split GEMM
#define NWIN 1584            // 528 q + 528 k + 528 v
#define KOUT 1056            // 528 lin + 528 win

typedef float f32x4 __attribute__((ext_vector_type(4)));
typedef short short8 __attribute__((ext_vector_type(8)));

__device__ inline ushort f2bf(float f) {
  uint u = __float_as_uint(f);
  uint r = u + 0x7fffu + ((u >> 16) & 1u);
  return (ushort)(r >> 16);
}
__device__ inline ushort f2bf_tr(float f) { return (ushort)(__float_as_uint(f) >> 16); }
__device__ inline float bf2f(ushort u) { return __uint_as_float(((uint)u) << 16); }

// ---------------- x fp32 [M][528] -> bf16 hi/lo [M][544] zero-padded -------------
__global__ __launch_bounds__(256) void x_cvt(const float* __restrict__ x,
                                             ushort* __restrict__ xhi,
                                             ushort* __restrict__ xlo, int M) {
  int total = M * KP;
  for (int i = blockIdx.x * 256 + threadIdx.x; i < total; i += gridDim.x * 256) {
    int row = i / KP, c = i - row * KP;
    float v = (c < DM) ? x[(size_t)row * DM + c] : 0.f;
    ushort h = f2bf(v);
    xhi[i] = h;
    xlo[i] = f2bf(v - bf2f(h));
  }
}

// ---------------- pack lin q|k weights, split layout [512][1632] -----------------
// k' in [0,544): W_hi ; [544,1088): W_hi ; [1088,1632): W_lo
__global__ __launch_bounds__(256) void pack_qks(const float* __restrict__ Wq,
                                                const float* __restrict__ Wk,
                                                ushort* __restrict__ dst) {
  int total = 512 * KSPLIT;
  for (int i = blockIdx.x * 256 + threadIdx.x; i < total; i += gridDim.x * 256) {
    int n = i / KSPLIT, kp = i - n * KSPLIT;
    int seg = kp / KP, kk = kp - seg * KP;
    float v = 0.f;
    if (kk < DM) v = (n < 256) ? Wq[(size_t)kk * 256 + n] : Wk[(size_t)kk * 256 + (n - 256)];
    ushort h = f2bf(v);
    if (seg == 2) h = f2bf(v - bf2f(h));
    dst[i] = h;
  }
}

// ---------------- Wv_lin [528][528] -> bf16 T [528][544] -------------------------
__global__ __launch_bounds__(256) void pack_v(const float* __restrict__ Wv,
                                              ushort* __restrict__ dst) {
  int total = DM * KP;
  for (int i = blockIdx.x * 256 + threadIdx.x; i < total; i += gridDim.x * 256) {
    int n = i / KP, k = i - n * KP;
    dst[i] = (k < DM) ? f2bf(Wv[(size_t)k * DM + n]) : (ushort)0;
  }
}

__global__ __launch_bounds__(256) void pack_win(const float* __restrict__ Wq,
                                                const float* __restrict__ Wk,
                                                const float* __restrict__ Wv,
                                                ushort* __restrict__ dst) {
  int total = NWIN * KP;
  for (int i = blockIdx.x * 256 + threadIdx.x; i < total; i += gridDim.x * 256) {
    int n = i / KP, k = i - n * KP;
    float v = 0.f;
    if (k < DM) {
      if (n < DM) v = Wq[(size_t)k * DM + n];
      else if (n < 2 * DM) v = Wk[(size_t)k * DM + (n - DM)];
      else v = Wv[(size_t)k * DM + (n - 2 * DM)];
    }
    dst[i] = f2bf(v);
  }
}

__global__ __launch_bounds__(256) void pack_out(const float* __restrict__ Wo_lin,
                                                const float* __restrict__ Wo_win,
                                                ushort* __restrict__ dst) {
  int total = DM * KOUT;
  for (int i = blockIdx.x * 256 + threadIdx.x; i < total; i += gridDim.x * 256) {
    int n = i / KOUT, k = i - n * KOUT;
    float v = (k < DM) ? Wo_lin[(size_t)k * DM + n] : Wo_win[(size_t)(k - DM) * DM + n];
    dst[i] = f2bf(v);
  }
}

// ---------------- split-bf16 GEMM for lin q/k: qk[M][512] fp32 -------------------
// A = [x_hi | x_lo | x_hi] (per k-segment), W = [W_hi | W_hi | W_lo]; BM=128 BN=64
__global__ __launch_bounds__(256) void gemm_qk_split(const ushort* __restrict__ xhi,
                                                     const ushort* __restrict__ xlo,
                                                     const ushort* __restrict__ Wsp,
                                                     float* __restrict__ qk, int M) {
  __shared__ ushort As[128][36];
  __shared__ ushort Bs[64][36];
  const int bm = blockIdx.x * 128, bn = blockIdx.y * 64;
  const int tid = threadIdx.x;
  const int lane = tid & 63, w = tid >> 6;
  const int lo = lane & 15, hi = lane >> 4;
  const int wr = w >> 1, wc = w & 1;
  f32x4 acc[4][2];
#pragma unroll
  for (int mb = 0; mb < 4; ++mb)
#pragma unroll
    for (int nb = 0; nb < 2; ++nb) acc[mb][nb] = (f32x4){0.f, 0.f, 0.f, 0.f};

  for (int k0 = 0; k0 < KSPLIT; k0 += 32) {
    const int seg = k0 / KP;
    const int kk = k0 - seg * KP;
    const ushort* xsrc = (seg == 1) ? xlo : xhi;
    short8 a_ld[2], b_ld;
#pragma unroll
    for (int p = 0; p < 2; ++p) {
      int c = tid + p * 256;
      int row = c >> 2, cc = c & 3;
      a_ld[p] = *(const short8*)&xsrc[(size_t)(bm + row) * KP + kk + cc * 8];
    }
    {
      int row = tid >> 2, cc = tid & 3;
      b_ld = *(const short8*)&Wsp[(size_t)(bn + row) * KSPLIT + k0 + cc * 8];
    }
    __syncthreads();
#pragma unroll
    for (int p = 0; p < 2; ++p) {
      int c = tid + p * 256;
      int row = c >> 2, cc = c & 3;
      *(short8*)&As[row][cc * 8] = a_ld[p];
    }
    {
      int row = tid >> 2, cc = tid & 3;
      *(short8*)&Bs[row][cc * 8] = b_ld;
    }
    __syncthreads();
    short8 afr[4], bfr[2];
#pragma unroll
    for (int mb = 0; mb < 4; ++mb) afr[mb] = *(const short8*)&As[wr * 64 + 16 * mb + lo][8 * hi];
#pragma unroll
    for (int nb = 0; nb < 2; ++nb) bfr[nb] = *(const short8*)&Bs[wc * 32 + 16 * nb + lo][8 * hi];
#pragma unroll
    for (int mb = 0; mb < 4; ++mb)
#pragma unroll
      for (int nb = 0; nb < 2; ++nb)
        acc[mb][nb] = __builtin_amdgcn_mfma_f32_16x16x32_bf16(afr[mb], bfr[nb], acc[mb][nb], 0, 0, 0);
  }
#pragma unroll
  for (int mb = 0; mb < 4; ++mb)
#pragma unroll
    for (int nb = 0; nb < 2; ++nb) {
      int col = bn + wc * 32 + 16 * nb + lo;
#pragma unroll
      for (int r = 0; r < 4; ++r) {
        int row = bm + wr * 64 + 16 * mb + 4 * hi + r;
        qk[(size_t)row * 512 + col] = acc[mb][nb][r];
      }
    }
}

// ---------------- bf16 MFMA GEMM 128x128, 4 waves --------------------------------
// MODE 0: win proj -> per-head bf16 layouts (q [bh][S][40] | k +maskbias | vT [bh][40][S])
// MODE 1: v_lin    -> fp32 store [M][528]
// MODE 2: out      -> fp32 direct store [M][528]
template<int MODE>
__global__ __launch_bounds__(256) void gemm_mfma(const ushort* __restrict__ A,
                                                 const ushort* __restrict__ Bt,
                                                 void* __restrict__ C0,
                                                 const int* __restrict__ maskp,
                                                 int Nvalid, int Kp, int S) {
  __shared__ ushort As[128][36];
  __shared__ ushort Bs[128][36];
  const int bm = blockIdx.x * 128, bn = blockIdx.y * 128;
  const int tid = threadIdx.x;
  const int lane = tid & 63, w = tid >> 6;
  const int lo = lane & 15, hi = lane >> 4;
  const int wr = w >> 1, wc = w & 1;
  f32x4 acc[4][4];
#pragma unroll
  for (int mb = 0; mb < 4; ++mb)
#pragma unroll
    for (int nb = 0; nb < 4; ++nb) acc[mb][nb] = (f32x4){0.f, 0.f, 0.f, 0.f};
  const short8 zv = {0, 0, 0, 0, 0, 0, 0, 0};

  for (int k0 = 0; k0 < Kp; k0 += 32) {
    short8 a_ld[2], b_ld[2];
#pragma unroll
    for (int p = 0; p < 2; ++p) {
      int c = tid + p * 256;
      int row = c >> 2, cc = c & 3;
      a_ld[p] = *(const short8*)&A[(size_t)(bm + row) * Kp + k0 + cc * 8];
      int bnr = bn + row;
      b_ld[p] = (bnr < Nvalid) ? *(const short8*)&Bt[(size_t)bnr * Kp + k0 + cc * 8] : zv;
    }
    __syncthreads();
#pragma unroll
    for (int p = 0; p < 2; ++p) {
      int c = tid + p * 256;
      int row = c >> 2, cc = c & 3;
      *(short8*)&As[row][cc * 8] = a_ld[p];
      *(short8*)&Bs[row][cc * 8] = b_ld[p];
    }
    __syncthreads();
    short8 afr[4], bfr[4];
#pragma unroll
    for (int mb = 0; mb < 4; ++mb) afr[mb] = *(const short8*)&As[wr * 64 + 16 * mb + lo][8 * hi];
#pragma unroll
    for (int nb = 0; nb < 4; ++nb) bfr[nb] = *(const short8*)&Bs[wc * 64 + 16 * nb + lo][8 * hi];
#pragma unroll
    for (int mb = 0; mb < 4; ++mb)
#pragma unroll
      for (int nb = 0; nb < 4; ++nb)
        acc[mb][nb] = __builtin_amdgcn_mfma_f32_16x16x32_bf16(afr[mb], bfr[nb], acc[mb][nb], 0, 0, 0);
  }

#pragma unroll
  for (int nb = 0; nb < 4; ++nb) {
    const int col = bn + wc * 64 + 16 * nb + lo;
    if (col >= Nvalid) continue;
    if (MODE == 1 || MODE == 2) {
      float* Cf = (float*)C0;
#pragma unroll
      for (int mb = 0; mb < 4; ++mb)
#pragma unroll
        for (int r = 0; r < 4; ++r) {
          int row = bm + wr * 64 + 16 * mb + 4 * hi + r;
          Cf[(size_t)row * DM + col] = acc[mb][nb][r];
        }
    } else {
      const int seg = col / DM;          // 0=q 1=k 2=v
      const int cc = col - seg * DM;
      const uint h = ((uint)cc * 993u) >> 15;
      const int e = cc - (int)h * 33;
      ushort* dst = (ushort*)C0 + (size_t)seg * (32u * (uint)S * 40u);
#pragma unroll
      for (int mb = 0; mb < 4; ++mb)
#pragma unroll
        for (int r = 0; r < 4; ++r) {
          int row = bm + wr * 64 + 16 * mb + 4 * hi + r;
          int b = (row >= S) ? 1 : 0;
          int nn = row - b * S;
          float val = acc[mb][nb][r];
          if (seg == 2) {
            size_t tb = (size_t)(b * NH + (int)h) * 40;
            dst[(tb + e) * S + nn] = f2bf(val);
            if (e == 0) {
              dst[(tb + 33) * S + nn] = 0x3F80;
#pragma unroll
              for (int z = 34; z < 40; ++z) dst[(tb + z) * S + nn] = 0;
            }
          } else {
            size_t base = ((size_t)(b * NH + (int)h) * S + nn) * 40;
            dst[base + e] = f2bf(val);
            if (e == 0) {
              ushort pad33 = (seg == 0) ? (ushort)0x3F80
                                        : (maskp[row] ? (ushort)0 : f2bf(-1e30f));
              dst[base + 33] = pad33;
#pragma unroll
              for (int z = 34; z < 40; ++z) dst[base + z] = 0;
            }
          }
        }
    }
  }
}

// ---------------- linear attention: partial kv over S-chunks ---------------------
__global__ __launch_bounds__(256) void lin_kv_part(const float* __restrict__ qk,
                                                   const float* __restrict__ v_lin,
                                                   float* __restrict__ kvp,
                                                   int B, int S) {
  const int bh = blockIdx.x, chunk = blockIdx.y;
  const int b = bh >> 4, h = bh & 15;
  const int tid = threadIdx.x;
  __shared__ float kraw[64][17];
  __shared__ float vsh[64][36];
  if (tid < 64) { vsh[tid][33] = 1.f; vsh[tid][34] = 0.f; vsh[tid][35] = 0.f; }
  f32x4 acc0 = {0.f, 0.f, 0.f, 0.f}, acc1 = {0.f, 0.f, 0.f, 0.f};
  const int d0 = tid / 9, c40 = (tid % 9) * 4;
  const int idx1 = tid + 256;
  const int d1 = idx1 / 9, c41 = (idx1 % 9) * 4;
  const int SC = S / 8;
  const int nbeg = chunk * SC;
  __syncthreads();
  for (int n0 = nbeg; n0 < nbeg + SC; n0 += 64) {
    {
      int row = tid >> 2, f4 = (tid & 3) * 4;
      float4 kv4 = *(const float4*)&qk[(size_t)(b * S + n0 + row) * 512 + 256 + h * 16 + f4];
      kraw[row][f4 + 0] = kv4.x; kraw[row][f4 + 1] = kv4.y;
      kraw[row][f4 + 2] = kv4.z; kraw[row][f4 + 3] = kv4.w;
    }
    for (int i = tid; i < 64 * 33; i += 256) {
      int n = i / 33, e = i - n * 33;
      vsh[n][e] = v_lin[(size_t)(b * S + n0 + n) * DM + h * HD + e];
    }
    __syncthreads();
#pragma unroll 4
    for (int n = 0; n < 64; ++n) {
      {
        float ke;
        if (d0 == 0) ke = 1.f;
        else if (d0 < 17) ke = kraw[n][d0 - 1];
        else { float kk = kraw[n][d0 - 17]; ke = 0.5f * kk * kk; }
        f32x4 v = *(const f32x4*)&vsh[n][c40];
        acc0 += ke * v;
      }
      if (idx1 < 297) {
        float ke;
        if (d1 < 17) ke = kraw[n][d1 - 1];
        else { float kk = kraw[n][d1 - 17]; ke = 0.5f * kk * kk; }
        f32x4 v = *(const f32x4*)&vsh[n][c41];
        acc1 += ke * v;
      }
    }
    __syncthreads();
  }
  float* dst = kvp + (size_t)(bh * 8 + chunk) * 1188;
  *(f32x4*)&dst[d0 * 36 + c40] = acc0;
  if (idx1 < 297) *(f32x4*)&dst[d1 * 36 + c41] = acc1;
}

__global__ __launch_bounds__(256) void lin_red(const float* __restrict__ kvp,
                                               float* __restrict__ kvr) {
  int bh = blockIdx.x;
  for (int i = threadIdx.x; i < 1188; i += 256) {
    float s = 0.f;
#pragma unroll
    for (int c = 0; c < 8; ++c) s += kvp[(size_t)(bh * 8 + c) * 1188 + i];
    kvr[(size_t)bh * 1188 + i] = s;
  }
}

// ---------------- linear attention output -> cat[:, 0:528] bf16 ------------------
__global__ __launch_bounds__(256) void lin_out_k(const float* __restrict__ qk,
                                                 const float* __restrict__ kvr,
                                                 const int* __restrict__ mask,
                                                 ushort* __restrict__ cat,
                                                 int B, int S) {
  const int bs = blockIdx.x;
  const int b = (bs >= S) ? 1 : 0;
  __shared__ float qsh[NH][17];
  for (int i = threadIdx.x; i < NH * FEAT; i += 256)
    qsh[i >> 4][i & 15] = qk[(size_t)bs * 512 + i];
  __syncthreads();
  const int msk = mask[bs];
  for (int o = threadIdx.x; o < DM; o += 256) {
    uint h = ((uint)o * 993u) >> 15;
    int e = o - (int)h * 33;
    const float* kvh = kvr + (size_t)(b * NH + (int)h) * 1188;
    float qsum = 1.f, qkv = kvh[e];
#pragma unroll
    for (int f = 0; f < FEAT; ++f) {
      float q = qsh[h][f];
      float q2 = 0.5f * q * q;
      qsum += q + q2;
      qkv += q * kvh[(1 + f) * 36 + e] + q2 * kvh[(17 + f) * 36 + e];
    }
    float z = qsum * kvh[e * 36 + 33];
    float outv = qkv / (z + EPSF);
    if (msk == 0) outv = 0.f;
    cat[(size_t)bs * KOUT + o] = f2bf(outv);
  }
}

// ---------------- banded attention: QBLK=128, split-K(4x8), static-max -----------
__global__ __launch_bounds__(256) void win_attn2(const ushort* __restrict__ qwb,
                                                 const ushort* __restrict__ kwb,
                                                 const ushort* __restrict__ vwbT,
                                                 ushort* __restrict__ Opart,
                                                 int S, int NT2) {
  const int qt = gridDim.x - 1 - blockIdx.x;
  const int bh = blockIdx.y;
  const int part = blockIdx.z;
  const int NT = NT2 * 2;
  const int T = min(NT, 2 * qt + 3);
  const int t0 = part * 8;
  if (t0 >= T) return;
  const int t1 = min(t0 + 8, T);
  const int n0 = qt * 128;
  const int tid = threadIdx.x;
  const int lane = tid & 63, w = tid >> 6;
  const int lo = lane & 15, hi = lane >> 4;

  __shared__ ushort Ks[64][72];
  __shared__ ushort Vt[48][72];
  __shared__ ushort Ps[4][32][72];
  for (int i = tid; i < 64 * 72; i += 256) ((ushort*)Ks)[i] = 0;
  for (int i = tid; i < 48 * 72; i += 256) ((ushort*)Vt)[i] = 0;

  short8 qf[2][2];
#pragma unroll
  for (int qr = 0; qr < 2; ++qr) {
    const ushort* qrow = qwb + ((size_t)bh * S + n0 + w * 32 + qr * 16 + lo) * 40;
    qf[qr][0] = *(const short8*)&qrow[8 * hi];
    qf[qr][1] = (hi == 0) ? *(const short8*)&qrow[32] : (short8){0, 0, 0, 0, 0, 0, 0, 0};
  }

  f32x4 Oacc[2][3];
#pragma unroll
  for (int qr = 0; qr < 2; ++qr)
#pragma unroll
    for (int eb = 0; eb < 3; ++eb) Oacc[qr][eb] = (f32x4){0.f, 0.f, 0.f, 0.f};
  __syncthreads();

  for (int t = t0; t < t1; ++t) {
    const int m0 = t * 64;
    for (int c = tid; c < 320; c += 256) {
      int row = c / 5, cc = c - row * 5;
      *(short8*)&Ks[row][cc * 8] =
          *(const short8*)&kwb[((size_t)bh * S + m0 + row) * 40 + cc * 8];
    }
    for (int c = tid; c < 320; c += 256) {
      int e = c >> 3, cc = c & 7;
      *(short8*)&Vt[e][cc * 8] =
          *(const short8*)&vwbT[((size_t)bh * 40 + e) * S + m0 + cc * 8];
    }
    __syncthreads();

    f32x4 accS[2][4];
#pragma unroll
    for (int qr = 0; qr < 2; ++qr)
#pragma unroll
      for (int bb = 0; bb < 4; ++bb) accS[qr][bb] = (f32x4){0.f, 0.f, 0.f, 0.f};
#pragma unroll
    for (int bb = 0; bb < 4; ++bb) {
      short8 kf0 = *(const short8*)&Ks[16 * bb + lo][8 * hi];
      short8 kf1 = *(const short8*)&Ks[16 * bb + lo][32 + 8 * hi];
#pragma unroll
      for (int qr = 0; qr < 2; ++qr) {
        accS[qr][bb] = __builtin_amdgcn_mfma_f32_16x16x32_bf16(qf[qr][0], kf0, accS[qr][bb], 0, 0, 0);
        accS[qr][bb] = __builtin_amdgcn_mfma_f32_16x16x32_bf16(qf[qr][1], kf1, accS[qr][bb], 0, 0, 0);
      }
    }

    const bool boundary = (m0 > n0);
    const int dmn = m0 - n0;
#pragma unroll
    for (int qr = 0; qr < 2; ++qr)
#pragma unroll
      for (int bb = 0; bb < 4; ++bb)
#pragma unroll
        for (int r = 0; r < 4; ++r) {
          float p = exp2f(fmaf(accS[qr][bb][r], K1C, -K2C));
          if (boundary) {
            int rr = w * 32 + qr * 16 + 4 * hi + r;
            int c = 16 * bb + lo;
            if (c > rr + 63 - dmn) p = 0.f;
          }
          Ps[w][qr * 16 + 4 * hi + r][16 * bb + lo] = f2bf_tr(p);
        }

#pragma unroll
    for (int qr = 0; qr < 2; ++qr) {
      short8 pf0 = *(const short8*)&Ps[w][qr * 16 + lo][8 * hi];
      short8 pf1 = *(const short8*)&Ps[w][qr * 16 + lo][32 + 8 * hi];
#pragma unroll
      for (int eb = 0; eb < 3; ++eb) {
        short8 vf0 = *(const short8*)&Vt[16 * eb + lo][8 * hi];
        short8 vf1 = *(const short8*)&Vt[16 * eb + lo][32 + 8 * hi];
        Oacc[qr][eb] = __builtin_amdgcn_mfma_f32_16x16x32_bf16(pf0, vf0, Oacc[qr][eb], 0, 0, 0);
        Oacc[qr][eb] = __builtin_amdgcn_mfma_f32_16x16x32_bf16(pf1, vf1, Oacc[qr][eb], 0, 0, 0);
      }
    }
    __syncthreads();
  }

  const size_t ob = ((size_t)(bh * NT2 + qt) * 4 + part) * 5120;
#pragma unroll
  for (int qr = 0; qr < 2; ++qr)
#pragma unroll
    for (int eb = 0; eb < 3; ++eb) {
      int e = 16 * eb + lo;
      if (e < 40) {
#pragma unroll
        for (int r = 0; r < 4; ++r)
          Opart[ob + (size_t)(w * 32 + qr * 16 + 4 * hi + r) * 40 + e] = f2bf(Oacc[qr][eb][r]);
      }
    }
}

// ---------------- combine partials -> cat[:, 528:1056] bf16 ----------------------
__global__ __launch_bounds__(256) void win_combine(const ushort* __restrict__ Opart,
                                                   ushort* __restrict__ cat,
                                                   int S, int NT2) {
  const int qt = blockIdx.x, bh = blockIdx.y;
  const int b = bh >> 4, h = bh & 15;
  const int T = min(NT2 * 2, 2 * qt + 3);
  const int P = min(4, (T + 7) >> 3);
  const size_t base = (size_t)(bh * NT2 + qt) * 4 * 5120;
  __shared__ float linv[128];
  const int tid = threadIdx.x;
  if (tid < 128) {
    float l = 0.f;
    for (int p = 0; p < P; ++p) l += bf2f(Opart[base + (size_t)p * 5120 + tid * 40 + 33]);
    linv[tid] = (l > 0.f) ? 1.f / l : 0.f;
  }
  __syncthreads();
  for (int i = tid; i < 128 * 33; i += 256) {
    int row = i / 33, e = i - row * 33;
    float o = 0.f;
    for (int p = 0; p < P; ++p) o += bf2f(Opart[base + (size_t)p * 5120 + row * 40 + e]);
    int n = qt * 128 + row;
    cat[((size_t)(b * S + n)) * KOUT + DM + h * HD + e] = f2bf(o * linv[row]);
  }
}

extern "C" void kernel_launch(void* const* d_in, const int* in_sizes, int n_in,
                              void* d_out, int out_size, void* d_ws, size_t ws_size,
                              hipStream_t stream) {
  const float* x      = (const float*)d_in[0];
  const int*   mask   = (const int*)d_in[1];
  const float* Wq_lin = (const float*)d_in[2];
  const float* Wk_lin = (const float*)d_in[3];
  const float* Wv_lin = (const float*)d_in[4];
  const float* Wo_lin = (const float*)d_in[5];
  const float* Wq_win = (const float*)d_in[6];
  const float* Wk_win = (const float*)d_in[7];
  const float* Wv_win = (const float*)d_in[8];
  const float* Wo_win = (const float*)d_in[9];
  float* out = (float*)d_out;

  const int BS = in_sizes[1];
  const int B = 2;
  const int S = BS / B;
  const int NT2 = S / 128;
  const int M = BS;

  // fp32 workspace
  float* ws = (float*)d_ws;
  float* qk      = ws;  ws += (size_t)BS * 512;
  float* v_lin   = ws;  ws += (size_t)BS * DM;
  float* kvp     = ws;  ws += (size_t)B * NH * 8 * 1188;
  float* kvr     = ws;  ws += (size_t)B * NH * 1188;
  // bf16 workspace
  ushort* ub    = (ushort*)ws;
  ushort* x_hi  = ub;  ub += (size_t)M * KP;
  ushort* x_lo  = ub;  ub += (size_t)M * KP;
  ushort* qkvw  = ub;  ub += (size_t)3 * 32 * S * 40;     // q | k | vT contiguous
  ushort* cat   = ub;  ub += (size_t)M * KOUT;
  ushort* WvT   = ub;  ub += (size_t)DM * KP;
  ushort* WwinT = ub;  ub += (size_t)NWIN * KP;
  ushort* WoT2  = ub;  ub += (size_t)DM * KOUT;
  ushort* Wqks  = ub;  ub += (size_t)512 * KSPLIT;
  ushort* Opart = ub;  ub += (size_t)32 * NT2 * 4 * 5120;

  ushort* qwb  = qkvw;
  ushort* kwb  = qkvw + (size_t)32 * S * 40;
  ushort* vwbT = qkvw + (size_t)64 * S * 40;

  dim3 blk(256);

  // conversions / weight packs
  x_cvt<<<2048, blk, 0, stream>>>(x, x_hi, x_lo, M);
  pack_qks<<<1024, blk, 0, stream>>>(Wq_lin, Wk_lin, Wqks);
  pack_v<<<1024, blk, 0, stream>>>(Wv_lin, WvT);
  pack_win<<<1536, blk, 0, stream>>>(Wq_win, Wk_win, Wv_win, WwinT);
  pack_out<<<1024, blk, 0, stream>>>(Wo_lin, Wo_win, WoT2);

  // linear path projections: q,k via split-bf16 MFMA; v via bf16 MFMA
  gemm_qk_split<<<dim3(M / 128, 8), blk, 0, stream>>>(x_hi, x_lo, Wqks, qk, M);
  gemm_mfma<1><<<dim3(M / 128, (DM + 127) / 128), blk, 0, stream>>>(
      x_hi, WvT, v_lin, nullptr, DM, KP, S);

  // window path projections (bf16, per-head layouts)
  gemm_mfma<0><<<dim3(M / 128, (NWIN + 127) / 128), blk, 0, stream>>>(
      x_hi, WwinT, qkvw, mask, NWIN, KP, S);

  // linear attention (fp32 math)
  lin_kv_part<<<dim3(B * NH, 8), blk, 0, stream>>>(qk, v_lin, kvp, B, S);
  lin_red<<<dim3(B * NH), blk, 0, stream>>>(kvp, kvr);
  lin_out_k<<<dim3(BS), blk, 0, stream>>>(qk, kvr, mask, cat, B, S);

  // banded attention
  win_attn2<<<dim3(NT2, B * NH, 4), blk, 0, stream>>>(qwb, kwb, vwbT, Opart, S, NT2);
  win_combine<<<dim3(NT2, B * NH), blk, 0, stream>>>(Opart, cat, S, NT2);

  // fused output projection: out = cat @ [Wo_lin; Wo_win]
  gemm_mfma<2><<<dim3(M / 128, (DM + 127) / 128), blk, 0, stream>>>(
      cat, WoT2, out, nullptr, DM, KOUT, S);
}

// Round 7
// 262.327 us; speedup vs baseline: 10.9102x; 1.0756x over previous
//
#include <hip/hip_runtime.h>

#define NH 16
#define FEAT 16
#define HD 33
#define DM 528
#define WIN 64
#define EPSF 1e-9f
#define K1C (0.17407765595569785f * 1.4426950408889634f)
#define KP 544               // padded K for projections
#define KSPLIT 1632          // 3*544 for hi/lo split GEMM
#define NWIN 1584            // 528 q + 528 k + 528 v
#define KOUT 1056            // 528 lin + 528 win

typedef float f32x4 __attribute__((ext_vector_type(4)));
typedef short short8 __attribute__((ext_vector_type(8)));

__device__ inline ushort f2bf(float f) {
  uint u = __float_as_uint(f);
  uint r = u + 0x7fffu + ((u >> 16) & 1u);
  return (ushort)(r >> 16);
}
__device__ inline ushort f2bf_tr(float f) { return (ushort)(__float_as_uint(f) >> 16); }
__device__ inline float bf2f(ushort u) { return __uint_as_float(((uint)u) << 16); }

// ---------------- fused prep: x hi/lo cvt + all weight packs ---------------------
__global__ __launch_bounds__(256) void prep_all(const float* __restrict__ x,
                                                const float* __restrict__ Wq_lin,
                                                const float* __restrict__ Wk_lin,
                                                const float* __restrict__ Wv_lin,
                                                const float* __restrict__ Wo_lin,
                                                const float* __restrict__ Wq_win,
                                                const float* __restrict__ Wk_win,
                                                const float* __restrict__ Wv_win,
                                                const float* __restrict__ Wo_win,
                                                ushort* __restrict__ xhi,
                                                ushort* __restrict__ xlo,
                                                ushort* __restrict__ Wqks,
                                                ushort* __restrict__ WvT,
                                                ushort* __restrict__ WwinT,
                                                ushort* __restrict__ WoT2, int M) {
  const int stride = gridDim.x * 256;
  const int tid0 = blockIdx.x * 256 + threadIdx.x;
  // 1. x -> bf16 hi/lo, padded [M][544]
  for (int i = tid0; i < M * KP; i += stride) {
    int row = i / KP, c = i - row * KP;
    float v = (c < DM) ? x[(size_t)row * DM + c] : 0.f;
    ushort h = f2bf(v);
    xhi[i] = h;
    xlo[i] = f2bf(v - bf2f(h));
  }
  // 2. lin q|k split weights [512][1632]
  for (int i = tid0; i < 512 * KSPLIT; i += stride) {
    int n = i / KSPLIT, kp = i - n * KSPLIT;
    int seg = kp / KP, kk = kp - seg * KP;
    float v = 0.f;
    if (kk < DM) v = (n < 256) ? Wq_lin[(size_t)kk * 256 + n] : Wk_lin[(size_t)kk * 256 + (n - 256)];
    ushort h = f2bf(v);
    if (seg == 2) h = f2bf(v - bf2f(h));
    Wqks[i] = h;
  }
  // 3. Wv_lin -> bf16 T [528][544]
  for (int i = tid0; i < DM * KP; i += stride) {
    int n = i / KP, k = i - n * KP;
    WvT[i] = (k < DM) ? f2bf(Wv_lin[(size_t)k * DM + n]) : (ushort)0;
  }
  // 4. win q|k|v weights [1584][544], K-seg pre-scaled by SCALE*log2e
  for (int i = tid0; i < NWIN * KP; i += stride) {
    int n = i / KP, k = i - n * KP;
    float v = 0.f;
    if (k < DM) {
      if (n < DM) v = Wq_win[(size_t)k * DM + n];
      else if (n < 2 * DM) v = Wk_win[(size_t)k * DM + (n - DM)] * K1C;
      else v = Wv_win[(size_t)k * DM + (n - 2 * DM)];
    }
    WwinT[i] = f2bf(v);
  }
  // 5. out weights [528][1056]
  for (int i = tid0; i < DM * KOUT; i += stride) {
    int n = i / KOUT, k = i - n * KOUT;
    float v = (k < DM) ? Wo_lin[(size_t)k * DM + n] : Wo_win[(size_t)(k - DM) * DM + n];
    WoT2[i] = f2bf(v);
  }
}

// ---------------- split-bf16 GEMM for lin q/k: qk[M][512] fp32 -------------------
__global__ __launch_bounds__(256) void gemm_qk_split(const ushort* __restrict__ xhi,
                                                     const ushort* __restrict__ xlo,
                                                     const ushort* __restrict__ Wsp,
                                                     float* __restrict__ qk, int M) {
  __shared__ ushort As[128][36];
  __shared__ ushort Bs[64][36];
  const int bm = blockIdx.x * 128, bn = blockIdx.y * 64;
  const int tid = threadIdx.x;
  const int lane = tid & 63, w = tid >> 6;
  const int lo = lane & 15, hi = lane >> 4;
  const int wr = w >> 1, wc = w & 1;
  f32x4 acc[4][2];
#pragma unroll
  for (int mb = 0; mb < 4; ++mb)
#pragma unroll
    for (int nb = 0; nb < 2; ++nb) acc[mb][nb] = (f32x4){0.f, 0.f, 0.f, 0.f};

  for (int k0 = 0; k0 < KSPLIT; k0 += 32) {
    const int seg = k0 / KP;
    const int kk = k0 - seg * KP;
    const ushort* xsrc = (seg == 1) ? xlo : xhi;
    short8 a_ld[2], b_ld;
#pragma unroll
    for (int p = 0; p < 2; ++p) {
      int c = tid + p * 256;
      int row = c >> 2, cc = c & 3;
      a_ld[p] = *(const short8*)&xsrc[(size_t)(bm + row) * KP + kk + cc * 8];
    }
    {
      int row = tid >> 2, cc = tid & 3;
      b_ld = *(const short8*)&Wsp[(size_t)(bn + row) * KSPLIT + k0 + cc * 8];
    }
    __syncthreads();
#pragma unroll
    for (int p = 0; p < 2; ++p) {
      int c = tid + p * 256;
      int row = c >> 2, cc = c & 3;
      *(short8*)&As[row][cc * 8] = a_ld[p];
    }
    {
      int row = tid >> 2, cc = tid & 3;
      *(short8*)&Bs[row][cc * 8] = b_ld;
    }
    __syncthreads();
    short8 afr[4], bfr[2];
#pragma unroll
    for (int mb = 0; mb < 4; ++mb) afr[mb] = *(const short8*)&As[wr * 64 + 16 * mb + lo][8 * hi];
#pragma unroll
    for (int nb = 0; nb < 2; ++nb) bfr[nb] = *(const short8*)&Bs[wc * 32 + 16 * nb + lo][8 * hi];
#pragma unroll
    for (int mb = 0; mb < 4; ++mb)
#pragma unroll
      for (int nb = 0; nb < 2; ++nb)
        acc[mb][nb] = __builtin_amdgcn_mfma_f32_16x16x32_bf16(afr[mb], bfr[nb], acc[mb][nb], 0, 0, 0);
  }
#pragma unroll
  for (int mb = 0; mb < 4; ++mb)
#pragma unroll
    for (int nb = 0; nb < 2; ++nb) {
      int col = bn + wc * 32 + 16 * nb + lo;
#pragma unroll
      for (int r = 0; r < 4; ++r) {
        int row = bm + wr * 64 + 16 * mb + 4 * hi + r;
        qk[(size_t)row * 512 + col] = acc[mb][nb][r];
      }
    }
}

// ---------------- bf16 MFMA GEMM 128x128, 4 waves --------------------------------
// MODE 0: win proj -> per-head bf16 layouts (q [bh][S][40] | k +maskbias | vT [bh][40][S])
// MODE 1: v_lin    -> fp32 store [M][528]
// MODE 2: out      -> fp32 direct store [M][528]
template<int MODE>
__global__ __launch_bounds__(256) void gemm_mfma(const ushort* __restrict__ A,
                                                 const ushort* __restrict__ Bt,
                                                 void* __restrict__ C0,
                                                 const int* __restrict__ maskp,
                                                 int Nvalid, int Kp, int S) {
  __shared__ ushort As[128][36];
  __shared__ ushort Bs[128][36];
  const int bm = blockIdx.x * 128, bn = blockIdx.y * 128;
  const int tid = threadIdx.x;
  const int lane = tid & 63, w = tid >> 6;
  const int lo = lane & 15, hi = lane >> 4;
  const int wr = w >> 1, wc = w & 1;
  f32x4 acc[4][4];
#pragma unroll
  for (int mb = 0; mb < 4; ++mb)
#pragma unroll
    for (int nb = 0; nb < 4; ++nb) acc[mb][nb] = (f32x4){0.f, 0.f, 0.f, 0.f};
  const short8 zv = {0, 0, 0, 0, 0, 0, 0, 0};

  for (int k0 = 0; k0 < Kp; k0 += 32) {
    short8 a_ld[2], b_ld[2];
#pragma unroll
    for (int p = 0; p < 2; ++p) {
      int c = tid + p * 256;
      int row = c >> 2, cc = c & 3;
      a_ld[p] = *(const short8*)&A[(size_t)(bm + row) * Kp + k0 + cc * 8];
      int bnr = bn + row;
      b_ld[p] = (bnr < Nvalid) ? *(const short8*)&Bt[(size_t)bnr * Kp + k0 + cc * 8] : zv;
    }
    __syncthreads();
#pragma unroll
    for (int p = 0; p < 2; ++p) {
      int c = tid + p * 256;
      int row = c >> 2, cc = c & 3;
      *(short8*)&As[row][cc * 8] = a_ld[p];
      *(short8*)&Bs[row][cc * 8] = b_ld[p];
    }
    __syncthreads();
    short8 afr[4], bfr[4];
#pragma unroll
    for (int mb = 0; mb < 4; ++mb) afr[mb] = *(const short8*)&As[wr * 64 + 16 * mb + lo][8 * hi];
#pragma unroll
    for (int nb = 0; nb < 4; ++nb) bfr[nb] = *(const short8*)&Bs[wc * 64 + 16 * nb + lo][8 * hi];
#pragma unroll
    for (int mb = 0; mb < 4; ++mb)
#pragma unroll
      for (int nb = 0; nb < 4; ++nb)
        acc[mb][nb] = __builtin_amdgcn_mfma_f32_16x16x32_bf16(afr[mb], bfr[nb], acc[mb][nb], 0, 0, 0);
  }

#pragma unroll
  for (int nb = 0; nb < 4; ++nb) {
    const int col = bn + wc * 64 + 16 * nb + lo;
    if (col >= Nvalid) continue;
    if (MODE == 1 || MODE == 2) {
      float* Cf = (float*)C0;
#pragma unroll
      for (int mb = 0; mb < 4; ++mb)
#pragma unroll
        for (int r = 0; r < 4; ++r) {
          int row = bm + wr * 64 + 16 * mb + 4 * hi + r;
          Cf[(size_t)row * DM + col] = acc[mb][nb][r];
        }
    } else {
      const int seg = col / DM;          // 0=q 1=k 2=v
      const int cc = col - seg * DM;
      const uint h = ((uint)cc * 993u) >> 15;
      const int e = cc - (int)h * 33;
      ushort* dst = (ushort*)C0 + (size_t)seg * (32u * (uint)S * 40u);
#pragma unroll
      for (int mb = 0; mb < 4; ++mb)
#pragma unroll
        for (int r = 0; r < 4; ++r) {
          int row = bm + wr * 64 + 16 * mb + 4 * hi + r;
          int b = (row >= S) ? 1 : 0;
          int nn = row - b * S;
          float val = acc[mb][nb][r];
          if (seg == 2) {
            size_t tb = (size_t)(b * NH + (int)h) * 40;
            dst[(tb + e) * S + nn] = f2bf(val);
            if (e == 0) {
              dst[(tb + 33) * S + nn] = 0x3F80;
#pragma unroll
              for (int z = 34; z < 40; ++z) dst[(tb + z) * S + nn] = 0;
            }
          } else {
            size_t base = ((size_t)(b * NH + (int)h) * S + nn) * 40;
            dst[base + e] = f2bf(val);
            if (e == 0) {
              ushort pad33 = (seg == 0) ? (ushort)0x3F80
                                        : (maskp[row] ? (ushort)0 : f2bf(-1e30f));
              dst[base + 33] = pad33;
#pragma unroll
              for (int z = 34; z < 40; ++z) dst[base + z] = 0;
            }
          }
        }
    }
  }
}

// ---------------- linear attention: partial kv over S-chunks ---------------------
__global__ __launch_bounds__(256) void lin_kv_part(const float* __restrict__ qk,
                                                   const float* __restrict__ v_lin,
                                                   float* __restrict__ kvp,
                                                   int B, int S) {
  const int bh = blockIdx.x, chunk = blockIdx.y;
  const int b = bh >> 4, h = bh & 15;
  const int tid = threadIdx.x;
  __shared__ float kraw[64][17];
  __shared__ float vsh[64][36];
  if (tid < 64) { vsh[tid][33] = 1.f; vsh[tid][34] = 0.f; vsh[tid][35] = 0.f; }
  f32x4 acc0 = {0.f, 0.f, 0.f, 0.f}, acc1 = {0.f, 0.f, 0.f, 0.f};
  const int d0 = tid / 9, c40 = (tid % 9) * 4;
  const int idx1 = tid + 256;
  const int d1 = idx1 / 9, c41 = (idx1 % 9) * 4;
  const int SC = S / 8;
  const int nbeg = chunk * SC;
  __syncthreads();
  for (int n0 = nbeg; n0 < nbeg + SC; n0 += 64) {
    {
      int row = tid >> 2, f4 = (tid & 3) * 4;
      float4 kv4 = *(const float4*)&qk[(size_t)(b * S + n0 + row) * 512 + 256 + h * 16 + f4];
      kraw[row][f4 + 0] = kv4.x; kraw[row][f4 + 1] = kv4.y;
      kraw[row][f4 + 2] = kv4.z; kraw[row][f4 + 3] = kv4.w;
    }
    for (int i = tid; i < 64 * 33; i += 256) {
      int n = i / 33, e = i - n * 33;
      vsh[n][e] = v_lin[(size_t)(b * S + n0 + n) * DM + h * HD + e];
    }
    __syncthreads();
#pragma unroll 4
    for (int n = 0; n < 64; ++n) {
      {
        float ke;
        if (d0 == 0) ke = 1.f;
        else if (d0 < 17) ke = kraw[n][d0 - 1];
        else { float kk = kraw[n][d0 - 17]; ke = 0.5f * kk * kk; }
        f32x4 v = *(const f32x4*)&vsh[n][c40];
        acc0 += ke * v;
      }
      if (idx1 < 297) {
        float ke;
        if (d1 < 17) ke = kraw[n][d1 - 1];
        else { float kk = kraw[n][d1 - 17]; ke = 0.5f * kk * kk; }
        f32x4 v = *(const f32x4*)&vsh[n][c41];
        acc1 += ke * v;
      }
    }
    __syncthreads();
  }
  float* dst = kvp + (size_t)(bh * 8 + chunk) * 1188;
  *(f32x4*)&dst[d0 * 36 + c40] = acc0;
  if (idx1 < 297) *(f32x4*)&dst[d1 * 36 + c41] = acc1;
}

__global__ __launch_bounds__(256) void lin_red(const float* __restrict__ kvp,
                                               float* __restrict__ kvr) {
  int bh = blockIdx.x;
  for (int i = threadIdx.x; i < 1188; i += 256) {
    float s = 0.f;
#pragma unroll
    for (int c = 0; c < 8; ++c) s += kvp[(size_t)(bh * 8 + c) * 1188 + i];
    kvr[(size_t)bh * 1188 + i] = s;
  }
}

// ---------------- linear attention output -> cat[:, 0:528] bf16 ------------------
__global__ __launch_bounds__(256) void lin_out_k(const float* __restrict__ qk,
                                                 const float* __restrict__ kvr,
                                                 const int* __restrict__ mask,
                                                 ushort* __restrict__ cat,
                                                 int B, int S) {
  const int bs = blockIdx.x;
  const int b = (bs >= S) ? 1 : 0;
  __shared__ float qsh[NH][17];
  for (int i = threadIdx.x; i < NH * FEAT; i += 256)
    qsh[i >> 4][i & 15] = qk[(size_t)bs * 512 + i];
  __syncthreads();
  const int msk = mask[bs];
  for (int o = threadIdx.x; o < DM; o += 256) {
    uint h = ((uint)o * 993u) >> 15;
    int e = o - (int)h * 33;
    const float* kvh = kvr + (size_t)(b * NH + (int)h) * 1188;
    float qsum = 1.f, qkv = kvh[e];
#pragma unroll
    for (int f = 0; f < FEAT; ++f) {
      float q = qsh[h][f];
      float q2 = 0.5f * q * q;
      qsum += q + q2;
      qkv += q * kvh[(1 + f) * 36 + e] + q2 * kvh[(17 + f) * 36 + e];
    }
    float z = qsum * kvh[e * 36 + 33];
    float outv = qkv / (z + EPSF);
    if (msk == 0) outv = 0.f;
    cat[(size_t)bs * KOUT + o] = f2bf(outv);
  }
}

// ---------------- banded attention: QBLK=128, split-K(4x8), reg-prefetch ---------
__global__ __launch_bounds__(256) void win_attn2(const ushort* __restrict__ qwb,
                                                 const ushort* __restrict__ kwb,
                                                 const ushort* __restrict__ vwbT,
                                                 ushort* __restrict__ Opart,
                                                 int S, int NT2) {
  const int qt = gridDim.x - 1 - blockIdx.x;
  const int bh = blockIdx.y;
  const int part = blockIdx.z;
  const int NT = NT2 * 2;
  const int T = min(NT, 2 * qt + 3);
  const int t0 = part * 8;
  if (t0 >= T) return;
  const int t1 = min(t0 + 8, T);
  const int n0 = qt * 128;
  const int tid = threadIdx.x;
  const int lane = tid & 63, w = tid >> 6;
  const int lo = lane & 15, hi = lane >> 4;

  __shared__ ushort Ks[64][40];      // K: rows kj, cols k-dim 0..39 (full real)
  __shared__ ushort Vt[40][72];      // V^T: rows e 0..39, cols kj 0..63
  __shared__ ushort Ps[4][32][72];   // per-wave P

  const short8 zv = {0, 0, 0, 0, 0, 0, 0, 0};

  // Q fragments
  short8 qf[2][2];
#pragma unroll
  for (int qr = 0; qr < 2; ++qr) {
    const ushort* qrow = qwb + ((size_t)bh * S + n0 + w * 32 + qr * 16 + lo) * 40;
    qf[qr][0] = *(const short8*)&qrow[8 * hi];
    qf[qr][1] = (hi == 0) ? *(const short8*)&qrow[32] : zv;
  }

  // staging geometry (K: 320 short8, V: 320 short8)
  const ushort* kbase = kwb + (size_t)bh * S * 40;
  const ushort* vbase = vwbT + (size_t)bh * 40 * S;
  const int kr0_row = tid / 5, kr0_cc = tid % 5;
  const bool p1v = (tid < 64);
  const int kr1_row = (tid + 256) / 5, kr1_cc = (tid + 256) % 5;
  const int vr0_e = tid >> 3, vr0_cc = tid & 7;
  const int vr1_e = (tid + 256) >> 3, vr1_cc = (tid + 256) & 7;
  short8 kreg[2], vreg[2];

#define ISSUE(tt) {                                                              \
    int m0_ = (tt) * 64;                                                         \
    kreg[0] = *(const short8*)&kbase[(size_t)(m0_ + kr0_row) * 40 + kr0_cc * 8]; \
    if (p1v) kreg[1] = *(const short8*)&kbase[(size_t)(m0_ + kr1_row) * 40 + kr1_cc * 8]; \
    vreg[0] = *(const short8*)&vbase[(size_t)vr0_e * S + m0_ + vr0_cc * 8];      \
    if (p1v) vreg[1] = *(const short8*)&vbase[(size_t)vr1_e * S + m0_ + vr1_cc * 8]; }

  f32x4 Oacc[2][3];
#pragma unroll
  for (int qr = 0; qr < 2; ++qr)
#pragma unroll
    for (int eb = 0; eb < 3; ++eb) Oacc[qr][eb] = (f32x4){0.f, 0.f, 0.f, 0.f};

  ISSUE(t0);

  for (int t = t0; t < t1; ++t) {
    __syncthreads();
    *(short8*)&Ks[kr0_row][kr0_cc * 8] = kreg[0];
    if (p1v) *(short8*)&Ks[kr1_row][kr1_cc * 8] = kreg[1];
    *(short8*)&Vt[vr0_e][vr0_cc * 8] = vreg[0];
    if (p1v) *(short8*)&Vt[vr1_e][vr1_cc * 8] = vreg[1];
    __syncthreads();
    if (t + 1 < t1) ISSUE(t + 1);

    const int m0 = t * 64;

    // QK^T (scale pre-folded into K weights)
    f32x4 accS[2][4];
#pragma unroll
    for (int qr = 0; qr < 2; ++qr)
#pragma unroll
      for (int bb = 0; bb < 4; ++bb) accS[qr][bb] = (f32x4){0.f, 0.f, 0.f, 0.f};
#pragma unroll
    for (int bb = 0; bb < 4; ++bb) {
      short8 kf0 = *(const short8*)&Ks[16 * bb + lo][8 * hi];
      short8 kf1 = (hi == 0) ? *(const short8*)&Ks[16 * bb + lo][32] : zv;
#pragma unroll
      for (int qr = 0; qr < 2; ++qr) {
        accS[qr][bb] = __builtin_amdgcn_mfma_f32_16x16x32_bf16(qf[qr][0], kf0, accS[qr][bb], 0, 0, 0);
        accS[qr][bb] = __builtin_amdgcn_mfma_f32_16x16x32_bf16(qf[qr][1], kf1, accS[qr][bb], 0, 0, 0);
      }
    }

    // P = exp2(s); band-edge mask on boundary tiles
    const bool boundary = (m0 > n0);
    const int dmn = m0 - n0;
#pragma unroll
    for (int qr = 0; qr < 2; ++qr)
#pragma unroll
      for (int bb = 0; bb < 4; ++bb)
#pragma unroll
        for (int r = 0; r < 4; ++r) {
          float p = exp2f(accS[qr][bb][r]);
          if (boundary) {
            int rr = w * 32 + qr * 16 + 4 * hi + r;
            int c = 16 * bb + lo;
            if (c > rr + 63 - dmn) p = 0.f;
          }
          Ps[w][qr * 16 + 4 * hi + r][16 * bb + lo] = f2bf_tr(p);
        }

    // PV (per-wave LDS, no barrier needed)
#pragma unroll
    for (int qr = 0; qr < 2; ++qr) {
      short8 pf0 = *(const short8*)&Ps[w][qr * 16 + lo][8 * hi];
      short8 pf1 = *(const short8*)&Ps[w][qr * 16 + lo][32 + 8 * hi];
#pragma unroll
      for (int eb = 0; eb < 3; ++eb) {
        const int e = 16 * eb + lo;
        short8 vf0 = (e < 40) ? *(const short8*)&Vt[e][8 * hi] : zv;
        short8 vf1 = (e < 40) ? *(const short8*)&Vt[e][32 + 8 * hi] : zv;
        Oacc[qr][eb] = __builtin_amdgcn_mfma_f32_16x16x32_bf16(pf0, vf0, Oacc[qr][eb], 0, 0, 0);
        Oacc[qr][eb] = __builtin_amdgcn_mfma_f32_16x16x32_bf16(pf1, vf1, Oacc[qr][eb], 0, 0, 0);
      }
    }
  }
#undef ISSUE

  const size_t ob = ((size_t)(bh * NT2 + qt) * 4 + part) * 5120;
#pragma unroll
  for (int qr = 0; qr < 2; ++qr)
#pragma unroll
    for (int eb = 0; eb < 3; ++eb) {
      int e = 16 * eb + lo;
      if (e < 40) {
#pragma unroll
        for (int r = 0; r < 4; ++r)
          Opart[ob + (size_t)(w * 32 + qr * 16 + 4 * hi + r) * 40 + e] = f2bf(Oacc[qr][eb][r]);
      }
    }
}

// ---------------- combine partials -> cat[:, 528:1056] bf16 ----------------------
__global__ __launch_bounds__(256) void win_combine(const ushort* __restrict__ Opart,
                                                   ushort* __restrict__ cat,
                                                   int S, int NT2) {
  const int qt = blockIdx.x, bh = blockIdx.y;
  const int b = bh >> 4, h = bh & 15;
  const int T = min(NT2 * 2, 2 * qt + 3);
  const int P = min(4, (T + 7) >> 3);
  const size_t base = (size_t)(bh * NT2 + qt) * 4 * 5120;
  __shared__ float linv[128];
  const int tid = threadIdx.x;
  if (tid < 128) {
    float l = 0.f;
    for (int p = 0; p < P; ++p) l += bf2f(Opart[base + (size_t)p * 5120 + tid * 40 + 33]);
    linv[tid] = (l > 0.f) ? 1.f / l : 0.f;
  }
  __syncthreads();
  for (int i = tid; i < 128 * 33; i += 256) {
    int row = i / 33, e = i - row * 33;
    float o = 0.f;
    for (int p = 0; p < P; ++p) o += bf2f(Opart[base + (size_t)p * 5120 + row * 40 + e]);
    int n = qt * 128 + row;
    cat[((size_t)(b * S + n)) * KOUT + DM + h * HD + e] = f2bf(o * linv[row]);
  }
}

extern "C" void kernel_launch(void* const* d_in, const int* in_sizes, int n_in,
                              void* d_out, int out_size, void* d_ws, size_t ws_size,
                              hipStream_t stream) {
  const float* x      = (const float*)d_in[0];
  const int*   mask   = (const int*)d_in[1];
  const float* Wq_lin = (const float*)d_in[2];
  const float* Wk_lin = (const float*)d_in[3];
  const float* Wv_lin = (const float*)d_in[4];
  const float* Wo_lin = (const float*)d_in[5];
  const float* Wq_win = (const float*)d_in[6];
  const float* Wk_win = (const float*)d_in[7];
  const float* Wv_win = (const float*)d_in[8];
  const float* Wo_win = (const float*)d_in[9];
  float* out = (float*)d_out;

  const int BS = in_sizes[1];
  const int B = 2;
  const int S = BS / B;
  const int NT2 = S / 128;
  const int M = BS;

  // fp32 workspace
  float* ws = (float*)d_ws;
  float* qk      = ws;  ws += (size_t)BS * 512;
  float* v_lin   = ws;  ws += (size_t)BS * DM;
  float* kvp     = ws;  ws += (size_t)B * NH * 8 * 1188;
  float* kvr     = ws;  ws += (size_t)B * NH * 1188;
  // bf16 workspace
  ushort* ub    = (ushort*)ws;
  ushort* x_hi  = ub;  ub += (size_t)M * KP;
  ushort* x_lo  = ub;  ub += (size_t)M * KP;
  ushort* qkvw  = ub;  ub += (size_t)3 * 32 * S * 40;     // q | k | vT contiguous
  ushort* cat   = ub;  ub += (size_t)M * KOUT;
  ushort* WvT   = ub;  ub += (size_t)DM * KP;
  ushort* WwinT = ub;  ub += (size_t)NWIN * KP;
  ushort* WoT2  = ub;  ub += (size_t)DM * KOUT;
  ushort* Wqks  = ub;  ub += (size_t)512 * KSPLIT;
  ushort* Opart = ub;  ub += (size_t)32 * NT2 * 4 * 5120;

  ushort* qwb  = qkvw;
  ushort* kwb  = qkvw + (size_t)32 * S * 40;
  ushort* vwbT = qkvw + (size_t)64 * S * 40;

  dim3 blk(256);

  // fused conversions / weight packs
  prep_all<<<2048, blk, 0, stream>>>(x, Wq_lin, Wk_lin, Wv_lin, Wo_lin,
                                     Wq_win, Wk_win, Wv_win, Wo_win,
                                     x_hi, x_lo, Wqks, WvT, WwinT, WoT2, M);

  // linear path projections: q,k via split-bf16 MFMA; v via bf16 MFMA
  gemm_qk_split<<<dim3(M / 128, 8), blk, 0, stream>>>(x_hi, x_lo, Wqks, qk, M);
  gemm_mfma<1><<<dim3(M / 128, (DM + 127) / 128), blk, 0, stream>>>(
      x_hi, WvT, v_lin, nullptr, DM, KP, S);

  // window path projections (bf16, per-head layouts)
  gemm_mfma<0><<<dim3(M / 128, (NWIN + 127) / 128), blk, 0, stream>>>(
      x_hi, WwinT, qkvw, mask, NWIN, KP, S);

  // linear attention (fp32 math)
  lin_kv_part<<<dim3(B * NH, 8), blk, 0, stream>>>(qk, v_lin, kvp, B, S);
  lin_red<<<dim3(B * NH), blk, 0, stream>>>(kvp, kvr);
  lin_out_k<<<dim3(BS), blk, 0, stream>>>(qk, kvr, mask, cat, B, S);

  // banded attention
  win_attn2<<<dim3(NT2, B * NH, 4), blk, 0, stream>>>(qwb, kwb, vwbT, Opart, S, NT2);
  win_combine<<<dim3(NT2, B * NH), blk, 0, stream>>>(Opart, cat, S, NT2);

  // fused output projection: out = cat @ [Wo_lin; Wo_win]
  gemm_mfma<2><<<dim3(M / 128, (DM + 127) / 128), blk, 0, stream>>>(
      cat, WoT2, out, nullptr, DM, KOUT, S);
}